// Round 10
// baseline (304.250 us; speedup 1.0000x reference)
//
#include <hip/hip_runtime.h>

// CSR-gather pipeline (no float atomics):
//   memset(bcnt,2KB) ; fill_a (x->fp16 cast + fixed-slot bucket staging) ;
//   fill_b2 (own-prefix over bcnt + per-bucket node hist + scan + ptr/dinv/csr) ;
//   gather32 ; h1tab (grid 256, measured-good) ; edge_mlp (R9: node-level
//   ptr/csr-ONLY prefetch, <=64 VGPR pinned) ; gcn2_gather
// R9 (resubmit — R9 bench was an infra failure, container died before running):
//     single change vs R8 — edge_mlp prefetches next node's ptr pair (iter top)
//     and csr tiles (post-MFMA), ~4 VGPR, launch_bounds(256,8) pins the 64-VGPR
//     cliff R1 crossed with its 8-VGPR atab prefetch. Serial chain/node: 3->1.

typedef __attribute__((ext_vector_type(8))) short short8;
typedef __attribute__((ext_vector_type(4))) float f32x4;
typedef __attribute__((ext_vector_type(8))) _Float16 f16x8;
typedef __attribute__((ext_vector_type(4))) _Float16 f16x4;
typedef __attribute__((ext_vector_type(2))) _Float16 f16x2;

#define FILL_CH 4096      // edges per fill_a block (256 thr x 16)

__device__ __forceinline__ unsigned short f2bf(float x) {   // RNE f32->bf16 (cold paths only)
    unsigned int u = __float_as_uint(x);
    return (unsigned short)((u + 0x7FFFu + ((u >> 16) & 1u)) >> 16);
}
__device__ __forceinline__ float bf2f(unsigned short h) {
    return __uint_as_float(((unsigned int)h) << 16);
}
// cheap truncation split: u ~= hi + lo with |err| ~ 2^-16 |u|
__device__ __forceinline__ void splitT(float u, short& hi, short& lo) {
    unsigned int ub = __float_as_uint(u);
    hi = (short)(ub >> 16);
    float r = u - __uint_as_float(ub & 0xFFFF0000u);
    lo = (short)(__float_as_uint(r) >> 16);
}
__device__ __forceinline__ f16x8 relu8(f16x8 v) {
    f16x8 z = {0, 0, 0, 0, 0, 0, 0, 0};
#if __has_builtin(__builtin_elementwise_max)
    return __builtin_elementwise_max(v, z);
#else
    f16x8 o;
#pragma unroll
    for (int j = 0; j < 8; ++j) o[j] = v[j] > (_Float16)0 ? v[j] : (_Float16)0;
    return o;
#endif
}

// rotate-add within a 16-lane row (DPP row_ror:N); tree 1,2,4,8 == full 16-lane
// sum in every lane. Pure VALU. (row_ror = 0x120+N.)
#define ROR_ADD(s, CTRL)                                                         \
    s += __int_as_float(__builtin_amdgcn_update_dpp(                             \
        0, __float_as_int(s), (CTRL), 0xf, 0xf, false))
#define ROR8_ADD(s) ROR_ADD(s, 0x128)

// fill phase A (+ x->fp16 cast): bucket edges into FIXED 4096-entry slots.
// stage entry packed: (r << 7) | (c & 127)   [valid for n < 2^25]
__global__ __launch_bounds__(256) void k_fill_a(
        const int* __restrict__ row, const int* __restrict__ col,
        const float4* __restrict__ x4, f16x4* __restrict__ xh4,
        int* __restrict__ bcnt, int* __restrict__ stage, int E, int m4, int nb) {
    __shared__ int cnt[512];
    __shared__ int base[512];
    int tid = threadIdx.x;
    // independent grid-stride cast (fills xh for gather32)
    int nth = gridDim.x * 256;
    for (int idx = blockIdx.x * 256 + tid; idx < m4; idx += nth) {
        float4 v = x4[idx];
        f16x4 o;
        o[0] = (_Float16)v.x; o[1] = (_Float16)v.y;
        o[2] = (_Float16)v.z; o[3] = (_Float16)v.w;
        xh4[idx] = o;
    }
    for (int i = tid; i < nb; i += 256) cnt[i] = 0;
    __syncthreads();
    int e0 = blockIdx.x * FILL_CH;
    int r[16], c[16];
#pragma unroll
    for (int i = 0; i < 16; ++i) {
        int e = e0 + tid + i * 256;
        if (e < E) {
            r[i] = row[e]; c[i] = col[e];
            atomicAdd(&cnt[c[i] >> 7], 1);
        } else c[i] = -1;
    }
    __syncthreads();
    for (int i = tid; i < nb; i += 256)
        base[i] = cnt[i] ? (i << 12) + atomicAdd(&bcnt[i], cnt[i]) : 0;
    __syncthreads();
    for (int i = tid; i < nb; i += 256) cnt[i] = 0;
    __syncthreads();
#pragma unroll
    for (int i = 0; i < 16; ++i) {
        if (c[i] >= 0) {
            int b = c[i] >> 7;
            int lp = atomicAdd(&cnt[b], 1);
            stage[base[b] + lp] = (r[i] << 7) | (c[i] & 127);
        }
    }
}

// fill phase B2: one block per bucket. Computes its OWN csr base (prefix sum of
// bcnt over buckets < b: 2 masked loads + wave butterfly), then local 128-col
// hist + exclusive scan -> ptr/dinv, then scatters csr via LDS cursors.
__global__ __launch_bounds__(256) void k_fill_b2(
        const int* __restrict__ bcnt, const int* __restrict__ stage,
        int* __restrict__ ptr, float* __restrict__ dinv, int* __restrict__ csr,
        int n, int nb, int E) {
    __shared__ int lcnt[128];
    __shared__ int lcur[128];
    __shared__ int wtotS;
    __shared__ int wsum[4];
    __shared__ int gbaseS;
    int b = blockIdx.x, tid = threadIdx.x;
    int lane = tid & 63, w = tid >> 6;
    int c0 = b << 7;
    int s0 = b << 12;               // fixed staging slot base
    int tot = bcnt[b];
    if (tid < 128) lcnt[tid] = 0;
    // own prefix: sum bcnt[i] for i < b (bcnt[i>=nb] is poisoned -> mask)
    int acc = 0;
    if (tid < b && tid < nb) acc += bcnt[tid];
    int t2 = tid + 256;
    if (t2 < b && t2 < nb) acc += bcnt[t2];
#pragma unroll
    for (int off = 1; off < 64; off <<= 1) acc += __shfl_xor(acc, off);
    if (lane == 0) wsum[w] = acc;
    __syncthreads();                // lcnt zeroed AND wsum ready
    if (tid == 0) {
        gbaseS = wsum[0] + wsum[1] + wsum[2] + wsum[3];
        if (b == nb - 1) ptr[n] = E;
    }
    for (int p = tid; p < tot; p += 256)
        atomicAdd(&lcnt[stage[s0 + p] & 127], 1);
    __syncthreads();                // hist done; gbaseS visible
    int gbase = gbaseS;
    int v = (tid < 128) ? lcnt[tid] : 0;
    int s = v;
    for (int off = 1; off < 64; off <<= 1) {
        int t = __shfl_up(s, off, 64);
        if (lane >= off) s += t;
    }
    if (tid == 63) wtotS = s;
    __syncthreads();
    int excl = s - v + ((w == 1) ? wtotS : 0);
    if (tid < 128) {
        int c = c0 + tid;
        int basep = gbase + excl;
        lcur[tid] = basep;
        if (c < n) {
            ptr[c] = basep;
            dinv[c] = rsqrtf((float)(v + 1));   // +1 self loop
        }
    }
    __syncthreads();
    for (int p = tid; p < tot; p += 256) {
        int vv = stage[s0 + p];
        int pos = atomicAdd(&lcur[vv & 127], 1);
        csr[pos] = vv >> 7;
    }
}

// irregular gather (fp16 x): agg[v] = dv*(sum dinv[r]*xh[r]) + dv^2*x[v]
__global__ __launch_bounds__(256) void k_gather32(
        const int* __restrict__ ptr, const int* __restrict__ csr_row,
        const float* __restrict__ x, const _Float16* __restrict__ xh,
        const float* __restrict__ dinv, float* __restrict__ agg, int n) {
    int wid = blockIdx.x * 4 + (threadIdx.x >> 6);
    if (wid >= n) return;
    int lane = threadIdx.x & 63;
    int f4 = lane & 7, slot = lane >> 3;
    int v = wid;
    int start = ptr[v], end = ptr[v + 1];
    const f16x4* xh4 = (const f16x4*)xh;
    float sx = 0.f, sy = 0.f, sz = 0.f, sw = 0.f;
    int p = start + slot;
    int r = (p < end) ? csr_row[p] : 0;
    while (p < end) {
        int rcur = r;
        int pn = p + 8;
        if (pn < end) r = csr_row[pn];
        float dr = dinv[rcur];
        f16x4 xv = xh4[(size_t)rcur * 8 + f4];
        sx = fmaf(dr, (float)xv[0], sx);
        sy = fmaf(dr, (float)xv[1], sy);
        sz = fmaf(dr, (float)xv[2], sz);
        sw = fmaf(dr, (float)xv[3], sw);
        p = pn;
    }
    ROR8_ADD(sx); ROR8_ADD(sy); ROR8_ADD(sz); ROR8_ADD(sw);
#pragma unroll
    for (int off = 16; off < 64; off <<= 1) {
        sx += __shfl_xor(sx, off); sy += __shfl_xor(sy, off);
        sz += __shfl_xor(sz, off); sw += __shfl_xor(sw, off);
    }
    if (slot == 0) {
        float dv = dinv[v], d2 = dv * dv;
        float4 xv = ((const float4*)x)[(size_t)v * 8 + f4];
        float4 o;
        o.x = dv * sx + d2 * xv.x;
        o.y = dv * sy + d2 * xv.y;
        o.z = dv * sz + d2 * xv.z;
        o.w = dv * sw + d2 * xv.w;
        ((float4*)agg)[(size_t)v * 8 + f4] = o;
    }
}

// FUSED dense MFMA: h1 = tanh(agg @ Wg1 + gb) ; atab = h1@(W1a-W1b)+b1 ;
// btab = h1@W1b (fp16 out). Wave-private LDS tile for C/D->A transform.
__global__ __launch_bounds__(256, 1) void k_h1tab(
        const float* __restrict__ agg, const float* __restrict__ gw,
        const float* __restrict__ gb, const float* __restrict__ w1,
        const float* __restrict__ b1,
        _Float16* __restrict__ atab, _Float16* __restrict__ btab, int ntiles) {
    __shared__ float tileS[4][16 * 66];
    int lane = threadIdx.x & 63;
    int wv = threadIdx.x >> 6;
    int n16 = lane & 15, q = lane >> 4;
    float* T = tileS[wv];

    short8 gh[4], gl[4];
    float gbias[4];
#pragma unroll
    for (int t = 0; t < 4; ++t) {
        gbias[t] = gb[t * 16 + n16];
        short8 hh, ll;
#pragma unroll
        for (int j = 0; j < 8; ++j) {
            float w = gw[(q * 8 + j) * 64 + t * 16 + n16];
            unsigned short wh = f2bf(w);
            hh[j] = (short)wh;
            ll[j] = (short)f2bf(w - bf2f(wh));
        }
        gh[t] = hh; gl[t] = ll;
    }
    short8 th[4][2], tl[4][2], uh[4][2], ul[4][2];
    float bias1[4];
#pragma unroll
    for (int t = 0; t < 4; ++t) {
        bias1[t] = b1[t * 16 + n16];
#pragma unroll
        for (int ck = 0; ck < 2; ++ck) {
            short8 h1v, l1v, h2v, l2v;
#pragma unroll
            for (int j = 0; j < 8; ++j) {
                int d = ck * 32 + q * 8 + j;
                float wbv = w1[(64 + d) * 64 + t * 16 + n16];
                float wtv = w1[d * 64 + t * 16 + n16] - wbv;
                unsigned short x1 = f2bf(wtv);
                h1v[j] = (short)x1; l1v[j] = (short)f2bf(wtv - bf2f(x1));
                unsigned short x2 = f2bf(wbv);
                h2v[j] = (short)x2; l2v[j] = (short)f2bf(wbv - bf2f(x2));
            }
            th[t][ck] = h1v; tl[t][ck] = l1v;
            uh[t][ck] = h2v; ul[t][ck] = l2v;
        }
    }

    int nwaves = gridDim.x * 4;
    int wid = blockIdx.x * 4 + wv;
    for (int tile = wid; tile < ntiles; tile += nwaves) {
        int v0 = tile * 16;
        const float4* a4 = (const float4*)(agg + (size_t)(v0 + n16) * 32);
        float4 A0 = a4[2 * q], A1 = a4[2 * q + 1];
        float a[8] = {A0.x, A0.y, A0.z, A0.w, A1.x, A1.y, A1.z, A1.w};
        short8 ah, al;
#pragma unroll
        for (int j = 0; j < 8; ++j) { short h, l; splitT(a[j], h, l); ah[j] = h; al[j] = l; }
#pragma unroll
        for (int t = 0; t < 4; ++t) {
            f32x4 acc = (f32x4){gbias[t], gbias[t], gbias[t], gbias[t]};
            acc = __builtin_amdgcn_mfma_f32_16x16x32_bf16(ah, gh[t], acc, 0, 0, 0);
            acc = __builtin_amdgcn_mfma_f32_16x16x32_bf16(al, gh[t], acc, 0, 0, 0);
            acc = __builtin_amdgcn_mfma_f32_16x16x32_bf16(ah, gl[t], acc, 0, 0, 0);
#pragma unroll
            for (int i = 0; i < 4; ++i)
                T[(q * 4 + i) * 66 + t * 16 + n16] = tanhf(acc[i]);
        }
        float b[16];
#pragma unroll
        for (int j = 0; j < 8; ++j) {
            b[j]     = T[n16 * 66 + q * 8 + j];
            b[8 + j] = T[n16 * 66 + 32 + q * 8 + j];
        }
        short8 ah0, ah1, al0, al1;
#pragma unroll
        for (int j = 0; j < 8; ++j) {
            short h, l;
            splitT(b[j], h, l);      ah0[j] = h; al0[j] = l;
            splitT(b[8 + j], h, l);  ah1[j] = h; al1[j] = l;
        }
#pragma unroll
        for (int t = 0; t < 4; ++t) {
            f32x4 aa = (f32x4){bias1[t], bias1[t], bias1[t], bias1[t]};
            aa = __builtin_amdgcn_mfma_f32_16x16x32_bf16(ah0, th[t][0], aa, 0, 0, 0);
            aa = __builtin_amdgcn_mfma_f32_16x16x32_bf16(ah1, th[t][1], aa, 0, 0, 0);
            aa = __builtin_amdgcn_mfma_f32_16x16x32_bf16(al0, th[t][0], aa, 0, 0, 0);
            aa = __builtin_amdgcn_mfma_f32_16x16x32_bf16(al1, th[t][1], aa, 0, 0, 0);
            aa = __builtin_amdgcn_mfma_f32_16x16x32_bf16(ah0, tl[t][0], aa, 0, 0, 0);
            aa = __builtin_amdgcn_mfma_f32_16x16x32_bf16(ah1, tl[t][1], aa, 0, 0, 0);
            f32x4 bb = (f32x4){0.f, 0.f, 0.f, 0.f};
            bb = __builtin_amdgcn_mfma_f32_16x16x32_bf16(ah0, uh[t][0], bb, 0, 0, 0);
            bb = __builtin_amdgcn_mfma_f32_16x16x32_bf16(ah1, uh[t][1], bb, 0, 0, 0);
            bb = __builtin_amdgcn_mfma_f32_16x16x32_bf16(al0, uh[t][0], bb, 0, 0, 0);
            bb = __builtin_amdgcn_mfma_f32_16x16x32_bf16(al1, uh[t][1], bb, 0, 0, 0);
            bb = __builtin_amdgcn_mfma_f32_16x16x32_bf16(ah0, ul[t][0], bb, 0, 0, 0);
            bb = __builtin_amdgcn_mfma_f32_16x16x32_bf16(ah1, ul[t][1], bb, 0, 0, 0);
#pragma unroll
            for (int i = 0; i < 4; ++i) {
                size_t off = (size_t)(v0 + q * 4 + i) * 64 + t * 16 + n16;
                atab[off] = (_Float16)aa[i];
                btab[off] = (_Float16)bb[i];
            }
        }
    }
}

// persistent waves; fp16 MFMA (fp32 acc, zero-C, bias after max); setprio;
// R9: node-level ptr/csr-ONLY prefetch (~4 VGPR), 64-VGPR cliff pinned via
// launch_bounds. Per-node serial chain: btab gather only.
__global__ __launch_bounds__(256, 8) void k_edge_mlp(
        const int* __restrict__ ptr, const int* __restrict__ csr_row,
        const _Float16* __restrict__ atab, const _Float16* __restrict__ btab,
        const float* __restrict__ w2, const float* __restrict__ b2,
        const float* __restrict__ wg, _Float16* __restrict__ h2h, int n) {
    int lane = threadIdx.x & 63;
    int n16 = lane & 15, q = lane >> 4;

    f16x8 wh[4][2];
    float bias[4];
    float wgf[4][4];    // Wg2 rows {t*16+n16}, cols {q*4+jj}
#pragma unroll
    for (int t = 0; t < 4; ++t) {
        bias[t] = b2[t * 16 + n16];
#pragma unroll
        for (int jj = 0; jj < 4; ++jj)
            wgf[t][jj] = wg[(t * 16 + n16) * 16 + q * 4 + jj];
#pragma unroll
        for (int ck = 0; ck < 2; ++ck) {
            f16x8 hh;
#pragma unroll
            for (int j = 0; j < 8; ++j)
                hh[j] = (_Float16)w2[(ck * 32 + q * 8 + j) * 64 + t * 16 + n16];
            wh[t][ck] = hh;
        }
    }
    const f32x4 z4 = (f32x4){0.f, 0.f, 0.f, 0.f};

    int nwaves = gridDim.x * 4;
    int wid = blockIdx.x * 4 + (threadIdx.x >> 6);
    if (wid >= n) return;

    // prologue: node `wid`'s ptr + both csr levels
    int c = wid;
    int st = ptr[c], ed = ptr[c + 1];
    {
        int deg = ed - st;
        int nf = deg >> 4, rm = deg & 15;
        int rrem0 = (rm > 0 && n16 < rm) ? csr_row[st + (nf << 4) + n16] : 0;
        int r0 = (nf > 0) ? csr_row[st + n16] : 0;
        // fallthrough into loop with (st,ed,r0,rrem0)
        int r = r0, rrem = rrem0;
        while (true) {
            // ---- prefetch next node's ptr pair (independent addresses) ----
            int cn = c + nwaves;
            bool hasN = cn < n;
            int stn = 0, edn = 0;
            if (hasN) { stn = ptr[cn]; edn = ptr[cn + 1]; }

            const f16x8* a8 = (const f16x8*)(atab + (size_t)c * 64);
            f16x8 A0 = a8[q], A1 = a8[4 + q];
            float red[4] = {0.f, 0.f, 0.f, 0.f};   // 0-init folds relu + empty-seg

            int deg2 = ed - st;
            int nfull = deg2 >> 4;
            int rem = deg2 & 15;
            for (int ft = 0; ft < nfull; ++ft) {
                int rcur = r;
                if (ft + 1 < nfull) r = csr_row[st + (ft + 1) * 16 + n16];
                const f16x8* b8 = (const f16x8*)(btab + (size_t)rcur * 64);
                f16x8 u0 = relu8(A0 + b8[q]);
                f16x8 u1 = relu8(A1 + b8[4 + q]);
                __builtin_amdgcn_s_setprio(1);
#pragma unroll
                for (int t = 0; t < 4; ++t) {
                    f32x4 a = __builtin_amdgcn_mfma_f32_16x16x32_f16(u0, wh[t][0], z4, 0, 0, 0);
                    a = __builtin_amdgcn_mfma_f32_16x16x32_f16(u1, wh[t][1], a, 0, 0, 0);
                    float mx = fmaxf(fmaxf(a[0], a[1]), fmaxf(a[2], a[3]));
                    red[t] = fmaxf(red[t], mx + bias[t]);
                }
                __builtin_amdgcn_s_setprio(0);
            }
            if (rem > 0) {
                f16x8 u0 = {0, 0, 0, 0, 0, 0, 0, 0};
                f16x8 u1 = {0, 0, 0, 0, 0, 0, 0, 0};
                if (n16 < rem) {
                    const f16x8* b8 = (const f16x8*)(btab + (size_t)rrem * 64);
                    u0 = relu8(A0 + b8[q]);
                    u1 = relu8(A1 + b8[4 + q]);
                }
                __builtin_amdgcn_s_setprio(1);
#pragma unroll
                for (int t = 0; t < 4; ++t) {
                    f32x4 a = __builtin_amdgcn_mfma_f32_16x16x32_f16(u0, wh[t][0], z4, 0, 0, 0);
                    a = __builtin_amdgcn_mfma_f32_16x16x32_f16(u1, wh[t][1], a, 0, 0, 0);
#pragma unroll
                    for (int i = 0; i < 4; ++i)
                        if (q * 4 + i < rem) red[t] = fmaxf(red[t], a[i] + bias[t]);
                }
                __builtin_amdgcn_s_setprio(0);
            }

            // ---- prefetch next node's csr (stn/edn arrived during MFMA) ----
            int rn = 0, rremn = 0;
            if (hasN) {
                int degn = edn - stn;
                int nfn = degn >> 4, rmn = degn & 15;
                if (rmn > 0 && n16 < rmn) rremn = csr_row[stn + (nfn << 4) + n16];
                if (nfn > 0) rn = csr_row[stn + n16];
            }

            // ---- epilogue: segment-max across q, fused GCN2, store ----
#pragma unroll
            for (int t = 0; t < 4; ++t) {
                red[t] = fmaxf(red[t], __shfl_xor(red[t], 16));
                red[t] = fmaxf(red[t], __shfl_xor(red[t], 32));
            }
            float part[4];
#pragma unroll
            for (int jj = 0; jj < 4; ++jj) {
                part[jj] = red[0] * wgf[0][jj];
                part[jj] = fmaf(red[1], wgf[1][jj], part[jj]);
                part[jj] = fmaf(red[2], wgf[2][jj], part[jj]);
                part[jj] = fmaf(red[3], wgf[3][jj], part[jj]);
                ROR_ADD(part[jj], 0x121);
                ROR_ADD(part[jj], 0x122);
                ROR_ADD(part[jj], 0x124);
                ROR_ADD(part[jj], 0x128);
            }
            if (n16 == 0) {
                f16x4 ph;
                ph[0] = (_Float16)part[0]; ph[1] = (_Float16)part[1];
                ph[2] = (_Float16)part[2]; ph[3] = (_Float16)part[3];
                ((f16x4*)(h2h + (size_t)c * 16))[q] = ph;
            }

            if (!hasN) break;
            c = cn; st = stn; ed = edn; r = rn; rrem = rremn;
        }
    }
}

// out[c] = bg + dv*(dv*h2[c] + sum_in dinv[r]*h2[r]) ; fully writes d_out
__global__ __launch_bounds__(256) void k_gcn2_gather(
        const int* __restrict__ ptr, const int* __restrict__ csr_row,
        const _Float16* __restrict__ h2h, const float* __restrict__ dinv,
        const float* __restrict__ bg, float* __restrict__ out, int n) {
    int wid = blockIdx.x * 4 + (threadIdx.x >> 6);
    if (wid >= n) return;
    int lane = threadIdx.x & 63;
    int f2 = lane & 7, slot = lane >> 3;
    int c = wid;
    int start = ptr[c], end = ptr[c + 1];
    const f16x2* h22 = (const f16x2*)h2h;
    float sx = 0.f, sy = 0.f;
    int p = start + slot;
    int r = (p < end) ? csr_row[p] : 0;
    while (p < end) {
        int rcur = r;
        int pn = p + 8;
        if (pn < end) r = csr_row[pn];
        float dr = dinv[rcur];
        f16x2 hv = h22[(size_t)rcur * 8 + f2];
        sx = fmaf(dr, (float)hv[0], sx);
        sy = fmaf(dr, (float)hv[1], sy);
        p = pn;
    }
    ROR8_ADD(sx); ROR8_ADD(sy);
#pragma unroll
    for (int off = 16; off < 64; off <<= 1) {
        sx += __shfl_xor(sx, off);
        sy += __shfl_xor(sy, off);
    }
    if (slot == 0) {
        float dv = dinv[c];
        f16x2 hv = h22[(size_t)c * 8 + f2];
        float2 o;
        o.x = bg[2 * f2]     + dv * (dv * (float)hv[0] + sx);
        o.y = bg[2 * f2 + 1] + dv * (dv * (float)hv[1] + sy);
        ((float2*)out)[(size_t)c * 8 + f2] = o;
    }
}

extern "C" void kernel_launch(void* const* d_in, const int* in_sizes, int n_in,
                              void* d_out, int out_size, void* d_ws, size_t ws_size,
                              hipStream_t stream) {
    const float* x   = (const float*)d_in[0];
    const int*   ei  = (const int*)d_in[1];
    const float* g1w = (const float*)d_in[2];
    const float* g1b = (const float*)d_in[3];
    const float* ew1 = (const float*)d_in[4];
    const float* eb1 = (const float*)d_in[5];
    const float* ew2 = (const float*)d_in[6];
    const float* eb2 = (const float*)d_in[7];
    const float* g2w = (const float*)d_in[8];
    const float* g2b = (const float*)d_in[9];
    float* out = (float*)d_out;
    float* ws  = (float*)d_ws;

    const int n = in_sizes[0] / 32;      // 50000
    const int E = in_sizes[1] / 2;       // 800000
    const int* row = ei;
    const int* col = ei + E;
    const int ntiles = (n + 15) / 16;    // 3125
    const int nbuck = (n + 127) >> 7;    // 391 buckets of 128 cols

    size_t npad    = ((size_t)n + 63) & ~(size_t)63;
    size_t o_misc  = 0;                         // bcnt[512]
    size_t o_ptr   = 1024;                      // n+1 (+pad)
    size_t o_csr   = o_ptr + npad + 64;         // E ints
    size_t o_dinv  = o_csr + (size_t)E;
    size_t o_atab  = o_dinv + npad;             // n*64 fp16 = n*32 floats
    size_t o_btab  = o_atab + (size_t)n * 32;   // n*64 fp16
    size_t o_agg   = o_btab + (size_t)n * 32;   // n*32 fp32
    size_t o_xh    = o_agg + (size_t)n * 32;    // n*32 fp16 = n*16 floats
    size_t o_h2h   = o_xh + (size_t)n * 16;     // n*16 fp16 = n*8 floats
    size_t o_stage = o_h2h + (size_t)n * 8;     // nbuck*4096 ints (fixed slots)

    int*      bcnt   = (int*)(ws + o_misc);
    int*      ptr    = (int*)(ws + o_ptr);
    int*      csr    = (int*)(ws + o_csr);
    float*    dinv   = ws + o_dinv;
    _Float16* atab   = (_Float16*)(ws + o_atab);
    _Float16* btab   = (_Float16*)(ws + o_btab);
    float*    agg    = ws + o_agg;
    _Float16* xh     = (_Float16*)(ws + o_xh);
    _Float16* h2h    = (_Float16*)(ws + o_h2h);
    int*      stage  = (int*)(ws + o_stage);

    int nblk = (n + 3) / 4;                      // wave-per-node kernels, 4 waves/block
    int fill_nb = (E + FILL_CH - 1) / FILL_CH;   // 196
    int m4 = n * 8;                              // x float4 count

    hipMemsetAsync(bcnt, 0, 512 * sizeof(int), stream);
    k_fill_a<<<fill_nb, 256, 0, stream>>>(row, col, (const float4*)x, (f16x4*)xh,
                                          bcnt, stage, E, m4, nbuck);
    k_fill_b2<<<nbuck, 256, 0, stream>>>(bcnt, stage, ptr, dinv, csr, n, nbuck, E);
    k_gather32<<<nblk, 256, 0, stream>>>(ptr, csr, x, xh, dinv, agg, n);
    k_h1tab<<<256, 256, 0, stream>>>(agg, g1w, g1b, ew1, eb1, atab, btab, ntiles);
    k_edge_mlp<<<2048, 256, 0, stream>>>(ptr, csr, atab, btab, ew2, eb2, g2w, h2h, n);
    k_gcn2_gather<<<nblk, 256, 0, stream>>>(ptr, csr, h2h, dinv, g2b, out, n);
}

// Round 11
// 187.249 us; speedup vs baseline: 1.6248x; 1.6248x over previous
//
#include <hip/hip_runtime.h>

// CSR-gather pipeline (no float atomics):
//   memset(bcnt,2KB) ; fill_a (x->fp16 cast + fixed-slot bucket staging) ;
//   fill_b2 (own-prefix over bcnt + per-bucket node hist + scan + ptr/dinv/csr) ;
//   gather32 ; h1tab (grid 256, measured-good) ; edge_mlp (ptr/csr prefetch,
//   NATURAL register allocation) ; gcn2_gather
// R11: R10's 304us was the launch_bounds(256,8) pin: gfx950's unified VGPR+AGPR
//     budget got split ~32/32, spilling the 32-VGPR weight array to scratch
//     (FETCH 34->362MB). The pin is removed (plain launch_bounds(256)); the
//     ptr/csr prefetch itself (~4 VGPR on R8's 56) is now measured cleanly.

typedef __attribute__((ext_vector_type(8))) short short8;
typedef __attribute__((ext_vector_type(4))) float f32x4;
typedef __attribute__((ext_vector_type(8))) _Float16 f16x8;
typedef __attribute__((ext_vector_type(4))) _Float16 f16x4;
typedef __attribute__((ext_vector_type(2))) _Float16 f16x2;

#define FILL_CH 4096      // edges per fill_a block (256 thr x 16)

__device__ __forceinline__ unsigned short f2bf(float x) {   // RNE f32->bf16 (cold paths only)
    unsigned int u = __float_as_uint(x);
    return (unsigned short)((u + 0x7FFFu + ((u >> 16) & 1u)) >> 16);
}
__device__ __forceinline__ float bf2f(unsigned short h) {
    return __uint_as_float(((unsigned int)h) << 16);
}
// cheap truncation split: u ~= hi + lo with |err| ~ 2^-16 |u|
__device__ __forceinline__ void splitT(float u, short& hi, short& lo) {
    unsigned int ub = __float_as_uint(u);
    hi = (short)(ub >> 16);
    float r = u - __uint_as_float(ub & 0xFFFF0000u);
    lo = (short)(__float_as_uint(r) >> 16);
}
__device__ __forceinline__ f16x8 relu8(f16x8 v) {
    f16x8 z = {0, 0, 0, 0, 0, 0, 0, 0};
#if __has_builtin(__builtin_elementwise_max)
    return __builtin_elementwise_max(v, z);
#else
    f16x8 o;
#pragma unroll
    for (int j = 0; j < 8; ++j) o[j] = v[j] > (_Float16)0 ? v[j] : (_Float16)0;
    return o;
#endif
}

// rotate-add within a 16-lane row (DPP row_ror:N); tree 1,2,4,8 == full 16-lane
// sum in every lane. Pure VALU. (row_ror = 0x120+N.)
#define ROR_ADD(s, CTRL)                                                         \
    s += __int_as_float(__builtin_amdgcn_update_dpp(                             \
        0, __float_as_int(s), (CTRL), 0xf, 0xf, false))
#define ROR8_ADD(s) ROR_ADD(s, 0x128)

// fill phase A (+ x->fp16 cast): bucket edges into FIXED 4096-entry slots.
// stage entry packed: (r << 7) | (c & 127)   [valid for n < 2^25]
__global__ __launch_bounds__(256) void k_fill_a(
        const int* __restrict__ row, const int* __restrict__ col,
        const float4* __restrict__ x4, f16x4* __restrict__ xh4,
        int* __restrict__ bcnt, int* __restrict__ stage, int E, int m4, int nb) {
    __shared__ int cnt[512];
    __shared__ int base[512];
    int tid = threadIdx.x;
    // independent grid-stride cast (fills xh for gather32)
    int nth = gridDim.x * 256;
    for (int idx = blockIdx.x * 256 + tid; idx < m4; idx += nth) {
        float4 v = x4[idx];
        f16x4 o;
        o[0] = (_Float16)v.x; o[1] = (_Float16)v.y;
        o[2] = (_Float16)v.z; o[3] = (_Float16)v.w;
        xh4[idx] = o;
    }
    for (int i = tid; i < nb; i += 256) cnt[i] = 0;
    __syncthreads();
    int e0 = blockIdx.x * FILL_CH;
    int r[16], c[16];
#pragma unroll
    for (int i = 0; i < 16; ++i) {
        int e = e0 + tid + i * 256;
        if (e < E) {
            r[i] = row[e]; c[i] = col[e];
            atomicAdd(&cnt[c[i] >> 7], 1);
        } else c[i] = -1;
    }
    __syncthreads();
    for (int i = tid; i < nb; i += 256)
        base[i] = cnt[i] ? (i << 12) + atomicAdd(&bcnt[i], cnt[i]) : 0;
    __syncthreads();
    for (int i = tid; i < nb; i += 256) cnt[i] = 0;
    __syncthreads();
#pragma unroll
    for (int i = 0; i < 16; ++i) {
        if (c[i] >= 0) {
            int b = c[i] >> 7;
            int lp = atomicAdd(&cnt[b], 1);
            stage[base[b] + lp] = (r[i] << 7) | (c[i] & 127);
        }
    }
}

// fill phase B2: one block per bucket. Computes its OWN csr base (prefix sum of
// bcnt over buckets < b: 2 masked loads + wave butterfly), then local 128-col
// hist + exclusive scan -> ptr/dinv, then scatters csr via LDS cursors.
__global__ __launch_bounds__(256) void k_fill_b2(
        const int* __restrict__ bcnt, const int* __restrict__ stage,
        int* __restrict__ ptr, float* __restrict__ dinv, int* __restrict__ csr,
        int n, int nb, int E) {
    __shared__ int lcnt[128];
    __shared__ int lcur[128];
    __shared__ int wtotS;
    __shared__ int wsum[4];
    __shared__ int gbaseS;
    int b = blockIdx.x, tid = threadIdx.x;
    int lane = tid & 63, w = tid >> 6;
    int c0 = b << 7;
    int s0 = b << 12;               // fixed staging slot base
    int tot = bcnt[b];
    if (tid < 128) lcnt[tid] = 0;
    // own prefix: sum bcnt[i] for i < b (bcnt[i>=nb] is poisoned -> mask)
    int acc = 0;
    if (tid < b && tid < nb) acc += bcnt[tid];
    int t2 = tid + 256;
    if (t2 < b && t2 < nb) acc += bcnt[t2];
#pragma unroll
    for (int off = 1; off < 64; off <<= 1) acc += __shfl_xor(acc, off);
    if (lane == 0) wsum[w] = acc;
    __syncthreads();                // lcnt zeroed AND wsum ready
    if (tid == 0) {
        gbaseS = wsum[0] + wsum[1] + wsum[2] + wsum[3];
        if (b == nb - 1) ptr[n] = E;
    }
    for (int p = tid; p < tot; p += 256)
        atomicAdd(&lcnt[stage[s0 + p] & 127], 1);
    __syncthreads();                // hist done; gbaseS visible
    int gbase = gbaseS;
    int v = (tid < 128) ? lcnt[tid] : 0;
    int s = v;
    for (int off = 1; off < 64; off <<= 1) {
        int t = __shfl_up(s, off, 64);
        if (lane >= off) s += t;
    }
    if (tid == 63) wtotS = s;
    __syncthreads();
    int excl = s - v + ((w == 1) ? wtotS : 0);
    if (tid < 128) {
        int c = c0 + tid;
        int basep = gbase + excl;
        lcur[tid] = basep;
        if (c < n) {
            ptr[c] = basep;
            dinv[c] = rsqrtf((float)(v + 1));   // +1 self loop
        }
    }
    __syncthreads();
    for (int p = tid; p < tot; p += 256) {
        int vv = stage[s0 + p];
        int pos = atomicAdd(&lcur[vv & 127], 1);
        csr[pos] = vv >> 7;
    }
}

// irregular gather (fp16 x): agg[v] = dv*(sum dinv[r]*xh[r]) + dv^2*x[v]
__global__ __launch_bounds__(256) void k_gather32(
        const int* __restrict__ ptr, const int* __restrict__ csr_row,
        const float* __restrict__ x, const _Float16* __restrict__ xh,
        const float* __restrict__ dinv, float* __restrict__ agg, int n) {
    int wid = blockIdx.x * 4 + (threadIdx.x >> 6);
    if (wid >= n) return;
    int lane = threadIdx.x & 63;
    int f4 = lane & 7, slot = lane >> 3;
    int v = wid;
    int start = ptr[v], end = ptr[v + 1];
    const f16x4* xh4 = (const f16x4*)xh;
    float sx = 0.f, sy = 0.f, sz = 0.f, sw = 0.f;
    int p = start + slot;
    int r = (p < end) ? csr_row[p] : 0;
    while (p < end) {
        int rcur = r;
        int pn = p + 8;
        if (pn < end) r = csr_row[pn];
        float dr = dinv[rcur];
        f16x4 xv = xh4[(size_t)rcur * 8 + f4];
        sx = fmaf(dr, (float)xv[0], sx);
        sy = fmaf(dr, (float)xv[1], sy);
        sz = fmaf(dr, (float)xv[2], sz);
        sw = fmaf(dr, (float)xv[3], sw);
        p = pn;
    }
    ROR8_ADD(sx); ROR8_ADD(sy); ROR8_ADD(sz); ROR8_ADD(sw);
#pragma unroll
    for (int off = 16; off < 64; off <<= 1) {
        sx += __shfl_xor(sx, off); sy += __shfl_xor(sy, off);
        sz += __shfl_xor(sz, off); sw += __shfl_xor(sw, off);
    }
    if (slot == 0) {
        float dv = dinv[v], d2 = dv * dv;
        float4 xv = ((const float4*)x)[(size_t)v * 8 + f4];
        float4 o;
        o.x = dv * sx + d2 * xv.x;
        o.y = dv * sy + d2 * xv.y;
        o.z = dv * sz + d2 * xv.z;
        o.w = dv * sw + d2 * xv.w;
        ((float4*)agg)[(size_t)v * 8 + f4] = o;
    }
}

// FUSED dense MFMA: h1 = tanh(agg @ Wg1 + gb) ; atab = h1@(W1a-W1b)+b1 ;
// btab = h1@W1b (fp16 out). Wave-private LDS tile for C/D->A transform.
__global__ __launch_bounds__(256, 1) void k_h1tab(
        const float* __restrict__ agg, const float* __restrict__ gw,
        const float* __restrict__ gb, const float* __restrict__ w1,
        const float* __restrict__ b1,
        _Float16* __restrict__ atab, _Float16* __restrict__ btab, int ntiles) {
    __shared__ float tileS[4][16 * 66];
    int lane = threadIdx.x & 63;
    int wv = threadIdx.x >> 6;
    int n16 = lane & 15, q = lane >> 4;
    float* T = tileS[wv];

    short8 gh[4], gl[4];
    float gbias[4];
#pragma unroll
    for (int t = 0; t < 4; ++t) {
        gbias[t] = gb[t * 16 + n16];
        short8 hh, ll;
#pragma unroll
        for (int j = 0; j < 8; ++j) {
            float w = gw[(q * 8 + j) * 64 + t * 16 + n16];
            unsigned short wh = f2bf(w);
            hh[j] = (short)wh;
            ll[j] = (short)f2bf(w - bf2f(wh));
        }
        gh[t] = hh; gl[t] = ll;
    }
    short8 th[4][2], tl[4][2], uh[4][2], ul[4][2];
    float bias1[4];
#pragma unroll
    for (int t = 0; t < 4; ++t) {
        bias1[t] = b1[t * 16 + n16];
#pragma unroll
        for (int ck = 0; ck < 2; ++ck) {
            short8 h1v, l1v, h2v, l2v;
#pragma unroll
            for (int j = 0; j < 8; ++j) {
                int d = ck * 32 + q * 8 + j;
                float wbv = w1[(64 + d) * 64 + t * 16 + n16];
                float wtv = w1[d * 64 + t * 16 + n16] - wbv;
                unsigned short x1 = f2bf(wtv);
                h1v[j] = (short)x1; l1v[j] = (short)f2bf(wtv - bf2f(x1));
                unsigned short x2 = f2bf(wbv);
                h2v[j] = (short)x2; l2v[j] = (short)f2bf(wbv - bf2f(x2));
            }
            th[t][ck] = h1v; tl[t][ck] = l1v;
            uh[t][ck] = h2v; ul[t][ck] = l2v;
        }
    }

    int nwaves = gridDim.x * 4;
    int wid = blockIdx.x * 4 + wv;
    for (int tile = wid; tile < ntiles; tile += nwaves) {
        int v0 = tile * 16;
        const float4* a4 = (const float4*)(agg + (size_t)(v0 + n16) * 32);
        float4 A0 = a4[2 * q], A1 = a4[2 * q + 1];
        float a[8] = {A0.x, A0.y, A0.z, A0.w, A1.x, A1.y, A1.z, A1.w};
        short8 ah, al;
#pragma unroll
        for (int j = 0; j < 8; ++j) { short h, l; splitT(a[j], h, l); ah[j] = h; al[j] = l; }
#pragma unroll
        for (int t = 0; t < 4; ++t) {
            f32x4 acc = (f32x4){gbias[t], gbias[t], gbias[t], gbias[t]};
            acc = __builtin_amdgcn_mfma_f32_16x16x32_bf16(ah, gh[t], acc, 0, 0, 0);
            acc = __builtin_amdgcn_mfma_f32_16x16x32_bf16(al, gh[t], acc, 0, 0, 0);
            acc = __builtin_amdgcn_mfma_f32_16x16x32_bf16(ah, gl[t], acc, 0, 0, 0);
#pragma unroll
            for (int i = 0; i < 4; ++i)
                T[(q * 4 + i) * 66 + t * 16 + n16] = tanhf(acc[i]);
        }
        float b[16];
#pragma unroll
        for (int j = 0; j < 8; ++j) {
            b[j]     = T[n16 * 66 + q * 8 + j];
            b[8 + j] = T[n16 * 66 + 32 + q * 8 + j];
        }
        short8 ah0, ah1, al0, al1;
#pragma unroll
        for (int j = 0; j < 8; ++j) {
            short h, l;
            splitT(b[j], h, l);      ah0[j] = h; al0[j] = l;
            splitT(b[8 + j], h, l);  ah1[j] = h; al1[j] = l;
        }
#pragma unroll
        for (int t = 0; t < 4; ++t) {
            f32x4 aa = (f32x4){bias1[t], bias1[t], bias1[t], bias1[t]};
            aa = __builtin_amdgcn_mfma_f32_16x16x32_bf16(ah0, th[t][0], aa, 0, 0, 0);
            aa = __builtin_amdgcn_mfma_f32_16x16x32_bf16(ah1, th[t][1], aa, 0, 0, 0);
            aa = __builtin_amdgcn_mfma_f32_16x16x32_bf16(al0, th[t][0], aa, 0, 0, 0);
            aa = __builtin_amdgcn_mfma_f32_16x16x32_bf16(al1, th[t][1], aa, 0, 0, 0);
            aa = __builtin_amdgcn_mfma_f32_16x16x32_bf16(ah0, tl[t][0], aa, 0, 0, 0);
            aa = __builtin_amdgcn_mfma_f32_16x16x32_bf16(ah1, tl[t][1], aa, 0, 0, 0);
            f32x4 bb = (f32x4){0.f, 0.f, 0.f, 0.f};
            bb = __builtin_amdgcn_mfma_f32_16x16x32_bf16(ah0, uh[t][0], bb, 0, 0, 0);
            bb = __builtin_amdgcn_mfma_f32_16x16x32_bf16(ah1, uh[t][1], bb, 0, 0, 0);
            bb = __builtin_amdgcn_mfma_f32_16x16x32_bf16(al0, uh[t][0], bb, 0, 0, 0);
            bb = __builtin_amdgcn_mfma_f32_16x16x32_bf16(al1, uh[t][1], bb, 0, 0, 0);
            bb = __builtin_amdgcn_mfma_f32_16x16x32_bf16(ah0, ul[t][0], bb, 0, 0, 0);
            bb = __builtin_amdgcn_mfma_f32_16x16x32_bf16(ah1, ul[t][1], bb, 0, 0, 0);
#pragma unroll
            for (int i = 0; i < 4; ++i) {
                size_t off = (size_t)(v0 + q * 4 + i) * 64 + t * 16 + n16;
                atab[off] = (_Float16)aa[i];
                btab[off] = (_Float16)bb[i];
            }
        }
    }
}

// persistent waves; fp16 MFMA (fp32 acc, zero-C, bias after max); setprio;
// node-level ptr/csr prefetch; NATURAL register allocation (no waves pin —
// R10 showed pinning splits the unified VGPR+AGPR file and spills weights).
__global__ __launch_bounds__(256) void k_edge_mlp(
        const int* __restrict__ ptr, const int* __restrict__ csr_row,
        const _Float16* __restrict__ atab, const _Float16* __restrict__ btab,
        const float* __restrict__ w2, const float* __restrict__ b2,
        const float* __restrict__ wg, _Float16* __restrict__ h2h, int n) {
    int lane = threadIdx.x & 63;
    int n16 = lane & 15, q = lane >> 4;

    f16x8 wh[4][2];
    float bias[4];
    float wgf[4][4];    // Wg2 rows {t*16+n16}, cols {q*4+jj}
#pragma unroll
    for (int t = 0; t < 4; ++t) {
        bias[t] = b2[t * 16 + n16];
#pragma unroll
        for (int jj = 0; jj < 4; ++jj)
            wgf[t][jj] = wg[(t * 16 + n16) * 16 + q * 4 + jj];
#pragma unroll
        for (int ck = 0; ck < 2; ++ck) {
            f16x8 hh;
#pragma unroll
            for (int j = 0; j < 8; ++j)
                hh[j] = (_Float16)w2[(ck * 32 + q * 8 + j) * 64 + t * 16 + n16];
            wh[t][ck] = hh;
        }
    }
    const f32x4 z4 = (f32x4){0.f, 0.f, 0.f, 0.f};

    int nwaves = gridDim.x * 4;
    int wid = blockIdx.x * 4 + (threadIdx.x >> 6);
    if (wid >= n) return;

    // prologue: node `wid`'s ptr + both csr levels
    int c = wid;
    int st = ptr[c], ed = ptr[c + 1];
    {
        int deg = ed - st;
        int nf = deg >> 4, rm = deg & 15;
        int rrem0 = (rm > 0 && n16 < rm) ? csr_row[st + (nf << 4) + n16] : 0;
        int r0 = (nf > 0) ? csr_row[st + n16] : 0;
        // fallthrough into loop with (st,ed,r0,rrem0)
        int r = r0, rrem = rrem0;
        while (true) {
            // ---- prefetch next node's ptr pair (independent addresses) ----
            int cn = c + nwaves;
            bool hasN = cn < n;
            int stn = 0, edn = 0;
            if (hasN) { stn = ptr[cn]; edn = ptr[cn + 1]; }

            const f16x8* a8 = (const f16x8*)(atab + (size_t)c * 64);
            f16x8 A0 = a8[q], A1 = a8[4 + q];
            float red[4] = {0.f, 0.f, 0.f, 0.f};   // 0-init folds relu + empty-seg

            int deg2 = ed - st;
            int nfull = deg2 >> 4;
            int rem = deg2 & 15;
            for (int ft = 0; ft < nfull; ++ft) {
                int rcur = r;
                if (ft + 1 < nfull) r = csr_row[st + (ft + 1) * 16 + n16];
                const f16x8* b8 = (const f16x8*)(btab + (size_t)rcur * 64);
                f16x8 u0 = relu8(A0 + b8[q]);
                f16x8 u1 = relu8(A1 + b8[4 + q]);
                __builtin_amdgcn_s_setprio(1);
#pragma unroll
                for (int t = 0; t < 4; ++t) {
                    f32x4 a = __builtin_amdgcn_mfma_f32_16x16x32_f16(u0, wh[t][0], z4, 0, 0, 0);
                    a = __builtin_amdgcn_mfma_f32_16x16x32_f16(u1, wh[t][1], a, 0, 0, 0);
                    float mx = fmaxf(fmaxf(a[0], a[1]), fmaxf(a[2], a[3]));
                    red[t] = fmaxf(red[t], mx + bias[t]);
                }
                __builtin_amdgcn_s_setprio(0);
            }
            if (rem > 0) {
                f16x8 u0 = {0, 0, 0, 0, 0, 0, 0, 0};
                f16x8 u1 = {0, 0, 0, 0, 0, 0, 0, 0};
                if (n16 < rem) {
                    const f16x8* b8 = (const f16x8*)(btab + (size_t)rrem * 64);
                    u0 = relu8(A0 + b8[q]);
                    u1 = relu8(A1 + b8[4 + q]);
                }
                __builtin_amdgcn_s_setprio(1);
#pragma unroll
                for (int t = 0; t < 4; ++t) {
                    f32x4 a = __builtin_amdgcn_mfma_f32_16x16x32_f16(u0, wh[t][0], z4, 0, 0, 0);
                    a = __builtin_amdgcn_mfma_f32_16x16x32_f16(u1, wh[t][1], a, 0, 0, 0);
#pragma unroll
                    for (int i = 0; i < 4; ++i)
                        if (q * 4 + i < rem) red[t] = fmaxf(red[t], a[i] + bias[t]);
                }
                __builtin_amdgcn_s_setprio(0);
            }

            // ---- prefetch next node's csr (stn/edn arrived during MFMA) ----
            int rn = 0, rremn = 0;
            if (hasN) {
                int degn = edn - stn;
                int nfn = degn >> 4, rmn = degn & 15;
                if (rmn > 0 && n16 < rmn) rremn = csr_row[stn + (nfn << 4) + n16];
                if (nfn > 0) rn = csr_row[stn + n16];
            }

            // ---- epilogue: segment-max across q, fused GCN2, store ----
#pragma unroll
            for (int t = 0; t < 4; ++t) {
                red[t] = fmaxf(red[t], __shfl_xor(red[t], 16));
                red[t] = fmaxf(red[t], __shfl_xor(red[t], 32));
            }
            float part[4];
#pragma unroll
            for (int jj = 0; jj < 4; ++jj) {
                part[jj] = red[0] * wgf[0][jj];
                part[jj] = fmaf(red[1], wgf[1][jj], part[jj]);
                part[jj] = fmaf(red[2], wgf[2][jj], part[jj]);
                part[jj] = fmaf(red[3], wgf[3][jj], part[jj]);
                ROR_ADD(part[jj], 0x121);
                ROR_ADD(part[jj], 0x122);
                ROR_ADD(part[jj], 0x124);
                ROR_ADD(part[jj], 0x128);
            }
            if (n16 == 0) {
                f16x4 ph;
                ph[0] = (_Float16)part[0]; ph[1] = (_Float16)part[1];
                ph[2] = (_Float16)part[2]; ph[3] = (_Float16)part[3];
                ((f16x4*)(h2h + (size_t)c * 16))[q] = ph;
            }

            if (!hasN) break;
            c = cn; st = stn; ed = edn; r = rn; rrem = rremn;
        }
    }
}

// out[c] = bg + dv*(dv*h2[c] + sum_in dinv[r]*h2[r]) ; fully writes d_out
__global__ __launch_bounds__(256) void k_gcn2_gather(
        const int* __restrict__ ptr, const int* __restrict__ csr_row,
        const _Float16* __restrict__ h2h, const float* __restrict__ dinv,
        const float* __restrict__ bg, float* __restrict__ out, int n) {
    int wid = blockIdx.x * 4 + (threadIdx.x >> 6);
    if (wid >= n) return;
    int lane = threadIdx.x & 63;
    int f2 = lane & 7, slot = lane >> 3;
    int c = wid;
    int start = ptr[c], end = ptr[c + 1];
    const f16x2* h22 = (const f16x2*)h2h;
    float sx = 0.f, sy = 0.f;
    int p = start + slot;
    int r = (p < end) ? csr_row[p] : 0;
    while (p < end) {
        int rcur = r;
        int pn = p + 8;
        if (pn < end) r = csr_row[pn];
        float dr = dinv[rcur];
        f16x2 hv = h22[(size_t)rcur * 8 + f2];
        sx = fmaf(dr, (float)hv[0], sx);
        sy = fmaf(dr, (float)hv[1], sy);
        p = pn;
    }
    ROR8_ADD(sx); ROR8_ADD(sy);
#pragma unroll
    for (int off = 16; off < 64; off <<= 1) {
        sx += __shfl_xor(sx, off);
        sy += __shfl_xor(sy, off);
    }
    if (slot == 0) {
        float dv = dinv[c];
        f16x2 hv = h22[(size_t)c * 8 + f2];
        float2 o;
        o.x = bg[2 * f2]     + dv * (dv * (float)hv[0] + sx);
        o.y = bg[2 * f2 + 1] + dv * (dv * (float)hv[1] + sy);
        ((float2*)out)[(size_t)c * 8 + f2] = o;
    }
}

extern "C" void kernel_launch(void* const* d_in, const int* in_sizes, int n_in,
                              void* d_out, int out_size, void* d_ws, size_t ws_size,
                              hipStream_t stream) {
    const float* x   = (const float*)d_in[0];
    const int*   ei  = (const int*)d_in[1];
    const float* g1w = (const float*)d_in[2];
    const float* g1b = (const float*)d_in[3];
    const float* ew1 = (const float*)d_in[4];
    const float* eb1 = (const float*)d_in[5];
    const float* ew2 = (const float*)d_in[6];
    const float* eb2 = (const float*)d_in[7];
    const float* g2w = (const float*)d_in[8];
    const float* g2b = (const float*)d_in[9];
    float* out = (float*)d_out;
    float* ws  = (float*)d_ws;

    const int n = in_sizes[0] / 32;      // 50000
    const int E = in_sizes[1] / 2;       // 800000
    const int* row = ei;
    const int* col = ei + E;
    const int ntiles = (n + 15) / 16;    // 3125
    const int nbuck = (n + 127) >> 7;    // 391 buckets of 128 cols

    size_t npad    = ((size_t)n + 63) & ~(size_t)63;
    size_t o_misc  = 0;                         // bcnt[512]
    size_t o_ptr   = 1024;                      // n+1 (+pad)
    size_t o_csr   = o_ptr + npad + 64;         // E ints
    size_t o_dinv  = o_csr + (size_t)E;
    size_t o_atab  = o_dinv + npad;             // n*64 fp16 = n*32 floats
    size_t o_btab  = o_atab + (size_t)n * 32;   // n*64 fp16
    size_t o_agg   = o_btab + (size_t)n * 32;   // n*32 fp32
    size_t o_xh    = o_agg + (size_t)n * 32;    // n*32 fp16 = n*16 floats
    size_t o_h2h   = o_xh + (size_t)n * 16;     // n*16 fp16 = n*8 floats
    size_t o_stage = o_h2h + (size_t)n * 8;     // nbuck*4096 ints (fixed slots)

    int*      bcnt   = (int*)(ws + o_misc);
    int*      ptr    = (int*)(ws + o_ptr);
    int*      csr    = (int*)(ws + o_csr);
    float*    dinv   = ws + o_dinv;
    _Float16* atab   = (_Float16*)(ws + o_atab);
    _Float16* btab   = (_Float16*)(ws + o_btab);
    float*    agg    = ws + o_agg;
    _Float16* xh     = (_Float16*)(ws + o_xh);
    _Float16* h2h    = (_Float16*)(ws + o_h2h);
    int*      stage  = (int*)(ws + o_stage);

    int nblk = (n + 3) / 4;                      // wave-per-node kernels, 4 waves/block
    int fill_nb = (E + FILL_CH - 1) / FILL_CH;   // 196
    int m4 = n * 8;                              // x float4 count

    hipMemsetAsync(bcnt, 0, 512 * sizeof(int), stream);
    k_fill_a<<<fill_nb, 256, 0, stream>>>(row, col, (const float4*)x, (f16x4*)xh,
                                          bcnt, stage, E, m4, nbuck);
    k_fill_b2<<<nbuck, 256, 0, stream>>>(bcnt, stage, ptr, dinv, csr, n, nbuck, E);
    k_gather32<<<nblk, 256, 0, stream>>>(ptr, csr, x, xh, dinv, agg, n);
    k_h1tab<<<256, 256, 0, stream>>>(agg, g1w, g1b, ew1, eb1, atab, btab, ntiles);
    k_edge_mlp<<<2048, 256, 0, stream>>>(ptr, csr, atab, btab, ew2, eb2, g2w, h2h, n);
    k_gcn2_gather<<<nblk, 256, 0, stream>>>(ptr, csr, h2h, dinv, g2b, out, n);
}

// Round 12
// 181.460 us; speedup vs baseline: 1.6767x; 1.0319x over previous
//
#include <hip/hip_runtime.h>

// CSR-gather pipeline (no float atomics):
//   memset(bcnt,2KB) ; fill_a (x->fp16 cast + fixed-slot bucket staging,
//   direct base[] cursors) ; fill_b2 (own-prefix + per-bucket hist/scan ->
//   ptr/dinv/csr) ; gather32 (persistent + prefetch) ; h1tab (grid 256) ;
//   edge_mlp (persistent + ptr/csr prefetch, natural regalloc) ;
//   gcn2_gather (persistent + prefetch)
// R12: R11's validated recipe (persistent waves + next-node ptr/csr-index
//     prefetch, indices only, natural allocation) applied to gather32 and
//     gcn2_gather (were 1-node-per-wave: 50k cold-start chains). fill_a
//     scatters via atomicAdd(base[]) directly (one fewer LDS pass+barrier).

typedef __attribute__((ext_vector_type(8))) short short8;
typedef __attribute__((ext_vector_type(4))) float f32x4;
typedef __attribute__((ext_vector_type(8))) _Float16 f16x8;
typedef __attribute__((ext_vector_type(4))) _Float16 f16x4;
typedef __attribute__((ext_vector_type(2))) _Float16 f16x2;

#define FILL_CH 4096      // edges per fill_a block (256 thr x 16)

__device__ __forceinline__ unsigned short f2bf(float x) {   // RNE f32->bf16 (cold paths only)
    unsigned int u = __float_as_uint(x);
    return (unsigned short)((u + 0x7FFFu + ((u >> 16) & 1u)) >> 16);
}
__device__ __forceinline__ float bf2f(unsigned short h) {
    return __uint_as_float(((unsigned int)h) << 16);
}
// cheap truncation split: u ~= hi + lo with |err| ~ 2^-16 |u|
__device__ __forceinline__ void splitT(float u, short& hi, short& lo) {
    unsigned int ub = __float_as_uint(u);
    hi = (short)(ub >> 16);
    float r = u - __uint_as_float(ub & 0xFFFF0000u);
    lo = (short)(__float_as_uint(r) >> 16);
}
__device__ __forceinline__ f16x8 relu8(f16x8 v) {
    f16x8 z = {0, 0, 0, 0, 0, 0, 0, 0};
#if __has_builtin(__builtin_elementwise_max)
    return __builtin_elementwise_max(v, z);
#else
    f16x8 o;
#pragma unroll
    for (int j = 0; j < 8; ++j) o[j] = v[j] > (_Float16)0 ? v[j] : (_Float16)0;
    return o;
#endif
}

// rotate-add within a 16-lane row (DPP row_ror:N); tree 1,2,4,8 == full 16-lane
// sum in every lane. Pure VALU. (row_ror = 0x120+N.)
#define ROR_ADD(s, CTRL)                                                         \
    s += __int_as_float(__builtin_amdgcn_update_dpp(                             \
        0, __float_as_int(s), (CTRL), 0xf, 0xf, false))
#define ROR8_ADD(s) ROR_ADD(s, 0x128)

// fill phase A (+ x->fp16 cast): bucket edges into FIXED 4096-entry slots.
// stage entry packed: (r << 7) | (c & 127)   [valid for n < 2^25]
// R12: scatter cursors ride directly on base[] (atomicAdd) — no 2nd cnt pass.
__global__ __launch_bounds__(256) void k_fill_a(
        const int* __restrict__ row, const int* __restrict__ col,
        const float4* __restrict__ x4, f16x4* __restrict__ xh4,
        int* __restrict__ bcnt, int* __restrict__ stage, int E, int m4, int nb) {
    __shared__ int cnt[512];
    __shared__ int base[512];
    int tid = threadIdx.x;
    // independent grid-stride cast (fills xh for gather32)
    int nth = gridDim.x * 256;
    for (int idx = blockIdx.x * 256 + tid; idx < m4; idx += nth) {
        float4 v = x4[idx];
        f16x4 o;
        o[0] = (_Float16)v.x; o[1] = (_Float16)v.y;
        o[2] = (_Float16)v.z; o[3] = (_Float16)v.w;
        xh4[idx] = o;
    }
    for (int i = tid; i < nb; i += 256) cnt[i] = 0;
    __syncthreads();
    int e0 = blockIdx.x * FILL_CH;
    int r[16], c[16];
#pragma unroll
    for (int i = 0; i < 16; ++i) {
        int e = e0 + tid + i * 256;
        if (e < E) {
            r[i] = row[e]; c[i] = col[e];
            atomicAdd(&cnt[c[i] >> 7], 1);
        } else c[i] = -1;
    }
    __syncthreads();
    for (int i = tid; i < nb; i += 256)
        base[i] = cnt[i] ? (i << 12) + atomicAdd(&bcnt[i], cnt[i]) : 0;
    __syncthreads();
#pragma unroll
    for (int i = 0; i < 16; ++i) {
        if (c[i] >= 0) {
            int b = c[i] >> 7;
            int lp = atomicAdd(&base[b], 1);
            stage[lp] = (r[i] << 7) | (c[i] & 127);
        }
    }
}

// fill phase B2: one block per bucket. Computes its OWN csr base (prefix sum of
// bcnt over buckets < b: 2 masked loads + wave butterfly), then local 128-col
// hist + exclusive scan -> ptr/dinv, then scatters csr via LDS cursors.
__global__ __launch_bounds__(256) void k_fill_b2(
        const int* __restrict__ bcnt, const int* __restrict__ stage,
        int* __restrict__ ptr, float* __restrict__ dinv, int* __restrict__ csr,
        int n, int nb, int E) {
    __shared__ int lcnt[128];
    __shared__ int lcur[128];
    __shared__ int wtotS;
    __shared__ int wsum[4];
    __shared__ int gbaseS;
    int b = blockIdx.x, tid = threadIdx.x;
    int lane = tid & 63, w = tid >> 6;
    int c0 = b << 7;
    int s0 = b << 12;               // fixed staging slot base
    int tot = bcnt[b];
    if (tid < 128) lcnt[tid] = 0;
    // own prefix: sum bcnt[i] for i < b (bcnt[i>=nb] is poisoned -> mask)
    int acc = 0;
    if (tid < b && tid < nb) acc += bcnt[tid];
    int t2 = tid + 256;
    if (t2 < b && t2 < nb) acc += bcnt[t2];
#pragma unroll
    for (int off = 1; off < 64; off <<= 1) acc += __shfl_xor(acc, off);
    if (lane == 0) wsum[w] = acc;
    __syncthreads();                // lcnt zeroed AND wsum ready
    if (tid == 0) {
        gbaseS = wsum[0] + wsum[1] + wsum[2] + wsum[3];
        if (b == nb - 1) ptr[n] = E;
    }
    for (int p = tid; p < tot; p += 256)
        atomicAdd(&lcnt[stage[s0 + p] & 127], 1);
    __syncthreads();                // hist done; gbaseS visible
    int gbase = gbaseS;
    int v = (tid < 128) ? lcnt[tid] : 0;
    int s = v;
    for (int off = 1; off < 64; off <<= 1) {
        int t = __shfl_up(s, off, 64);
        if (lane >= off) s += t;
    }
    if (tid == 63) wtotS = s;
    __syncthreads();
    int excl = s - v + ((w == 1) ? wtotS : 0);
    if (tid < 128) {
        int c = c0 + tid;
        int basep = gbase + excl;
        lcur[tid] = basep;
        if (c < n) {
            ptr[c] = basep;
            dinv[c] = rsqrtf((float)(v + 1));   // +1 self loop
        }
    }
    __syncthreads();
    for (int p = tid; p < tot; p += 256) {
        int vv = stage[s0 + p];
        int pos = atomicAdd(&lcur[vv & 127], 1);
        csr[pos] = vv >> 7;
    }
}

// irregular gather (fp16 x): agg[v] = dv*(sum dinv[r]*xh[r]) + dv^2*x[v]
// R12: persistent waves + next-node ptr/first-csr prefetch (R11 recipe).
__global__ __launch_bounds__(256) void k_gather32(
        const int* __restrict__ ptr, const int* __restrict__ csr_row,
        const float* __restrict__ x, const _Float16* __restrict__ xh,
        const float* __restrict__ dinv, float* __restrict__ agg, int n) {
    int lane = threadIdx.x & 63;
    int f4 = lane & 7, slot = lane >> 3;
    const f16x4* xh4 = (const f16x4*)xh;

    int nwaves = gridDim.x * 4;
    int wid = blockIdx.x * 4 + (threadIdx.x >> 6);
    if (wid >= n) return;

    int c = wid;
    int st = ptr[c], ed = ptr[c + 1];
    int r0 = (st + slot < ed) ? csr_row[st + slot] : 0;
    while (true) {
        // prefetch next node's ptr pair
        int cn = c + nwaves;
        bool hasN = cn < n;
        int stn = 0, edn = 0;
        if (hasN) { stn = ptr[cn]; edn = ptr[cn + 1]; }

        float sx = 0.f, sy = 0.f, sz = 0.f, sw = 0.f;
        int p = st + slot;
        int r = r0;
        while (p < ed) {
            int rcur = r;
            int pn = p + 8;
            if (pn < ed) r = csr_row[pn];
            float dr = dinv[rcur];
            f16x4 xv = xh4[(size_t)rcur * 8 + f4];
            sx = fmaf(dr, (float)xv[0], sx);
            sy = fmaf(dr, (float)xv[1], sy);
            sz = fmaf(dr, (float)xv[2], sz);
            sw = fmaf(dr, (float)xv[3], sw);
            p = pn;
        }
        // prefetch next node's first csr batch
        int r0n = 0;
        if (hasN && stn + slot < edn) r0n = csr_row[stn + slot];

        ROR8_ADD(sx); ROR8_ADD(sy); ROR8_ADD(sz); ROR8_ADD(sw);
#pragma unroll
        for (int off = 16; off < 64; off <<= 1) {
            sx += __shfl_xor(sx, off); sy += __shfl_xor(sy, off);
            sz += __shfl_xor(sz, off); sw += __shfl_xor(sw, off);
        }
        if (slot == 0) {
            float dv = dinv[c], d2 = dv * dv;
            float4 xv = ((const float4*)x)[(size_t)c * 8 + f4];
            float4 o;
            o.x = dv * sx + d2 * xv.x;
            o.y = dv * sy + d2 * xv.y;
            o.z = dv * sz + d2 * xv.z;
            o.w = dv * sw + d2 * xv.w;
            ((float4*)agg)[(size_t)c * 8 + f4] = o;
        }
        if (!hasN) break;
        c = cn; st = stn; ed = edn; r0 = r0n;
    }
}

// FUSED dense MFMA: h1 = tanh(agg @ Wg1 + gb) ; atab = h1@(W1a-W1b)+b1 ;
// btab = h1@W1b (fp16 out). Wave-private LDS tile for C/D->A transform.
__global__ __launch_bounds__(256, 1) void k_h1tab(
        const float* __restrict__ agg, const float* __restrict__ gw,
        const float* __restrict__ gb, const float* __restrict__ w1,
        const float* __restrict__ b1,
        _Float16* __restrict__ atab, _Float16* __restrict__ btab, int ntiles) {
    __shared__ float tileS[4][16 * 66];
    int lane = threadIdx.x & 63;
    int wv = threadIdx.x >> 6;
    int n16 = lane & 15, q = lane >> 4;
    float* T = tileS[wv];

    short8 gh[4], gl[4];
    float gbias[4];
#pragma unroll
    for (int t = 0; t < 4; ++t) {
        gbias[t] = gb[t * 16 + n16];
        short8 hh, ll;
#pragma unroll
        for (int j = 0; j < 8; ++j) {
            float w = gw[(q * 8 + j) * 64 + t * 16 + n16];
            unsigned short wh = f2bf(w);
            hh[j] = (short)wh;
            ll[j] = (short)f2bf(w - bf2f(wh));
        }
        gh[t] = hh; gl[t] = ll;
    }
    short8 th[4][2], tl[4][2], uh[4][2], ul[4][2];
    float bias1[4];
#pragma unroll
    for (int t = 0; t < 4; ++t) {
        bias1[t] = b1[t * 16 + n16];
#pragma unroll
        for (int ck = 0; ck < 2; ++ck) {
            short8 h1v, l1v, h2v, l2v;
#pragma unroll
            for (int j = 0; j < 8; ++j) {
                int d = ck * 32 + q * 8 + j;
                float wbv = w1[(64 + d) * 64 + t * 16 + n16];
                float wtv = w1[d * 64 + t * 16 + n16] - wbv;
                unsigned short x1 = f2bf(wtv);
                h1v[j] = (short)x1; l1v[j] = (short)f2bf(wtv - bf2f(x1));
                unsigned short x2 = f2bf(wbv);
                h2v[j] = (short)x2; l2v[j] = (short)f2bf(wbv - bf2f(x2));
            }
            th[t][ck] = h1v; tl[t][ck] = l1v;
            uh[t][ck] = h2v; ul[t][ck] = l2v;
        }
    }

    int nwaves = gridDim.x * 4;
    int wid = blockIdx.x * 4 + wv;
    for (int tile = wid; tile < ntiles; tile += nwaves) {
        int v0 = tile * 16;
        const float4* a4 = (const float4*)(agg + (size_t)(v0 + n16) * 32);
        float4 A0 = a4[2 * q], A1 = a4[2 * q + 1];
        float a[8] = {A0.x, A0.y, A0.z, A0.w, A1.x, A1.y, A1.z, A1.w};
        short8 ah, al;
#pragma unroll
        for (int j = 0; j < 8; ++j) { short h, l; splitT(a[j], h, l); ah[j] = h; al[j] = l; }
#pragma unroll
        for (int t = 0; t < 4; ++t) {
            f32x4 acc = (f32x4){gbias[t], gbias[t], gbias[t], gbias[t]};
            acc = __builtin_amdgcn_mfma_f32_16x16x32_bf16(ah, gh[t], acc, 0, 0, 0);
            acc = __builtin_amdgcn_mfma_f32_16x16x32_bf16(al, gh[t], acc, 0, 0, 0);
            acc = __builtin_amdgcn_mfma_f32_16x16x32_bf16(ah, gl[t], acc, 0, 0, 0);
#pragma unroll
            for (int i = 0; i < 4; ++i)
                T[(q * 4 + i) * 66 + t * 16 + n16] = tanhf(acc[i]);
        }
        float b[16];
#pragma unroll
        for (int j = 0; j < 8; ++j) {
            b[j]     = T[n16 * 66 + q * 8 + j];
            b[8 + j] = T[n16 * 66 + 32 + q * 8 + j];
        }
        short8 ah0, ah1, al0, al1;
#pragma unroll
        for (int j = 0; j < 8; ++j) {
            short h, l;
            splitT(b[j], h, l);      ah0[j] = h; al0[j] = l;
            splitT(b[8 + j], h, l);  ah1[j] = h; al1[j] = l;
        }
#pragma unroll
        for (int t = 0; t < 4; ++t) {
            f32x4 aa = (f32x4){bias1[t], bias1[t], bias1[t], bias1[t]};
            aa = __builtin_amdgcn_mfma_f32_16x16x32_bf16(ah0, th[t][0], aa, 0, 0, 0);
            aa = __builtin_amdgcn_mfma_f32_16x16x32_bf16(ah1, th[t][1], aa, 0, 0, 0);
            aa = __builtin_amdgcn_mfma_f32_16x16x32_bf16(al0, th[t][0], aa, 0, 0, 0);
            aa = __builtin_amdgcn_mfma_f32_16x16x32_bf16(al1, th[t][1], aa, 0, 0, 0);
            aa = __builtin_amdgcn_mfma_f32_16x16x32_bf16(ah0, tl[t][0], aa, 0, 0, 0);
            aa = __builtin_amdgcn_mfma_f32_16x16x32_bf16(ah1, tl[t][1], aa, 0, 0, 0);
            f32x4 bb = (f32x4){0.f, 0.f, 0.f, 0.f};
            bb = __builtin_amdgcn_mfma_f32_16x16x32_bf16(ah0, uh[t][0], bb, 0, 0, 0);
            bb = __builtin_amdgcn_mfma_f32_16x16x32_bf16(ah1, uh[t][1], bb, 0, 0, 0);
            bb = __builtin_amdgcn_mfma_f32_16x16x32_bf16(al0, uh[t][0], bb, 0, 0, 0);
            bb = __builtin_amdgcn_mfma_f32_16x16x32_bf16(al1, uh[t][1], bb, 0, 0, 0);
            bb = __builtin_amdgcn_mfma_f32_16x16x32_bf16(ah0, ul[t][0], bb, 0, 0, 0);
            bb = __builtin_amdgcn_mfma_f32_16x16x32_bf16(ah1, ul[t][1], bb, 0, 0, 0);
#pragma unroll
            for (int i = 0; i < 4; ++i) {
                size_t off = (size_t)(v0 + q * 4 + i) * 64 + t * 16 + n16;
                atab[off] = (_Float16)aa[i];
                btab[off] = (_Float16)bb[i];
            }
        }
    }
}

// persistent waves; fp16 MFMA (fp32 acc, zero-C, bias after max); setprio;
// node-level ptr/csr prefetch; NATURAL register allocation (no waves pin —
// R10 showed pinning splits the unified VGPR+AGPR file and spills weights).
__global__ __launch_bounds__(256) void k_edge_mlp(
        const int* __restrict__ ptr, const int* __restrict__ csr_row,
        const _Float16* __restrict__ atab, const _Float16* __restrict__ btab,
        const float* __restrict__ w2, const float* __restrict__ b2,
        const float* __restrict__ wg, _Float16* __restrict__ h2h, int n) {
    int lane = threadIdx.x & 63;
    int n16 = lane & 15, q = lane >> 4;

    f16x8 wh[4][2];
    float bias[4];
    float wgf[4][4];    // Wg2 rows {t*16+n16}, cols {q*4+jj}
#pragma unroll
    for (int t = 0; t < 4; ++t) {
        bias[t] = b2[t * 16 + n16];
#pragma unroll
        for (int jj = 0; jj < 4; ++jj)
            wgf[t][jj] = wg[(t * 16 + n16) * 16 + q * 4 + jj];
#pragma unroll
        for (int ck = 0; ck < 2; ++ck) {
            f16x8 hh;
#pragma unroll
            for (int j = 0; j < 8; ++j)
                hh[j] = (_Float16)w2[(ck * 32 + q * 8 + j) * 64 + t * 16 + n16];
            wh[t][ck] = hh;
        }
    }
    const f32x4 z4 = (f32x4){0.f, 0.f, 0.f, 0.f};

    int nwaves = gridDim.x * 4;
    int wid = blockIdx.x * 4 + (threadIdx.x >> 6);
    if (wid >= n) return;

    // prologue: node `wid`'s ptr + both csr levels
    int c = wid;
    int st = ptr[c], ed = ptr[c + 1];
    {
        int deg = ed - st;
        int nf = deg >> 4, rm = deg & 15;
        int rrem0 = (rm > 0 && n16 < rm) ? csr_row[st + (nf << 4) + n16] : 0;
        int r0 = (nf > 0) ? csr_row[st + n16] : 0;
        // fallthrough into loop with (st,ed,r0,rrem0)
        int r = r0, rrem = rrem0;
        while (true) {
            // ---- prefetch next node's ptr pair (independent addresses) ----
            int cn = c + nwaves;
            bool hasN = cn < n;
            int stn = 0, edn = 0;
            if (hasN) { stn = ptr[cn]; edn = ptr[cn + 1]; }

            const f16x8* a8 = (const f16x8*)(atab + (size_t)c * 64);
            f16x8 A0 = a8[q], A1 = a8[4 + q];
            float red[4] = {0.f, 0.f, 0.f, 0.f};   // 0-init folds relu + empty-seg

            int deg2 = ed - st;
            int nfull = deg2 >> 4;
            int rem = deg2 & 15;
            for (int ft = 0; ft < nfull; ++ft) {
                int rcur = r;
                if (ft + 1 < nfull) r = csr_row[st + (ft + 1) * 16 + n16];
                const f16x8* b8 = (const f16x8*)(btab + (size_t)rcur * 64);
                f16x8 u0 = relu8(A0 + b8[q]);
                f16x8 u1 = relu8(A1 + b8[4 + q]);
                __builtin_amdgcn_s_setprio(1);
#pragma unroll
                for (int t = 0; t < 4; ++t) {
                    f32x4 a = __builtin_amdgcn_mfma_f32_16x16x32_f16(u0, wh[t][0], z4, 0, 0, 0);
                    a = __builtin_amdgcn_mfma_f32_16x16x32_f16(u1, wh[t][1], a, 0, 0, 0);
                    float mx = fmaxf(fmaxf(a[0], a[1]), fmaxf(a[2], a[3]));
                    red[t] = fmaxf(red[t], mx + bias[t]);
                }
                __builtin_amdgcn_s_setprio(0);
            }
            if (rem > 0) {
                f16x8 u0 = {0, 0, 0, 0, 0, 0, 0, 0};
                f16x8 u1 = {0, 0, 0, 0, 0, 0, 0, 0};
                if (n16 < rem) {
                    const f16x8* b8 = (const f16x8*)(btab + (size_t)rrem * 64);
                    u0 = relu8(A0 + b8[q]);
                    u1 = relu8(A1 + b8[4 + q]);
                }
                __builtin_amdgcn_s_setprio(1);
#pragma unroll
                for (int t = 0; t < 4; ++t) {
                    f32x4 a = __builtin_amdgcn_mfma_f32_16x16x32_f16(u0, wh[t][0], z4, 0, 0, 0);
                    a = __builtin_amdgcn_mfma_f32_16x16x32_f16(u1, wh[t][1], a, 0, 0, 0);
#pragma unroll
                    for (int i = 0; i < 4; ++i)
                        if (q * 4 + i < rem) red[t] = fmaxf(red[t], a[i] + bias[t]);
                }
                __builtin_amdgcn_s_setprio(0);
            }

            // ---- prefetch next node's csr (stn/edn arrived during MFMA) ----
            int rn = 0, rremn = 0;
            if (hasN) {
                int degn = edn - stn;
                int nfn = degn >> 4, rmn = degn & 15;
                if (rmn > 0 && n16 < rmn) rremn = csr_row[stn + (nfn << 4) + n16];
                if (nfn > 0) rn = csr_row[stn + n16];
            }

            // ---- epilogue: segment-max across q, fused GCN2, store ----
#pragma unroll
            for (int t = 0; t < 4; ++t) {
                red[t] = fmaxf(red[t], __shfl_xor(red[t], 16));
                red[t] = fmaxf(red[t], __shfl_xor(red[t], 32));
            }
            float part[4];
#pragma unroll
            for (int jj = 0; jj < 4; ++jj) {
                part[jj] = red[0] * wgf[0][jj];
                part[jj] = fmaf(red[1], wgf[1][jj], part[jj]);
                part[jj] = fmaf(red[2], wgf[2][jj], part[jj]);
                part[jj] = fmaf(red[3], wgf[3][jj], part[jj]);
                ROR_ADD(part[jj], 0x121);
                ROR_ADD(part[jj], 0x122);
                ROR_ADD(part[jj], 0x124);
                ROR_ADD(part[jj], 0x128);
            }
            if (n16 == 0) {
                f16x4 ph;
                ph[0] = (_Float16)part[0]; ph[1] = (_Float16)part[1];
                ph[2] = (_Float16)part[2]; ph[3] = (_Float16)part[3];
                ((f16x4*)(h2h + (size_t)c * 16))[q] = ph;
            }

            if (!hasN) break;
            c = cn; st = stn; ed = edn; r = rn; rrem = rremn;
        }
    }
}

// out[c] = bg + dv*(dv*h2[c] + sum_in dinv[r]*h2[r]) ; fully writes d_out
// R12: persistent waves + next-node ptr/first-csr prefetch (R11 recipe).
__global__ __launch_bounds__(256) void k_gcn2_gather(
        const int* __restrict__ ptr, const int* __restrict__ csr_row,
        const _Float16* __restrict__ h2h, const float* __restrict__ dinv,
        const float* __restrict__ bg, float* __restrict__ out, int n) {
    int lane = threadIdx.x & 63;
    int f2 = lane & 7, slot = lane >> 3;
    const f16x2* h22 = (const f16x2*)h2h;

    int nwaves = gridDim.x * 4;
    int wid = blockIdx.x * 4 + (threadIdx.x >> 6);
    if (wid >= n) return;

    int c = wid;
    int st = ptr[c], ed = ptr[c + 1];
    int r0 = (st + slot < ed) ? csr_row[st + slot] : 0;
    while (true) {
        int cn = c + nwaves;
        bool hasN = cn < n;
        int stn = 0, edn = 0;
        if (hasN) { stn = ptr[cn]; edn = ptr[cn + 1]; }

        float sx = 0.f, sy = 0.f;
        int p = st + slot;
        int r = r0;
        while (p < ed) {
            int rcur = r;
            int pn = p + 8;
            if (pn < ed) r = csr_row[pn];
            float dr = dinv[rcur];
            f16x2 hv = h22[(size_t)rcur * 8 + f2];
            sx = fmaf(dr, (float)hv[0], sx);
            sy = fmaf(dr, (float)hv[1], sy);
            p = pn;
        }
        int r0n = 0;
        if (hasN && stn + slot < edn) r0n = csr_row[stn + slot];

        ROR8_ADD(sx); ROR8_ADD(sy);
#pragma unroll
        for (int off = 16; off < 64; off <<= 1) {
            sx += __shfl_xor(sx, off);
            sy += __shfl_xor(sy, off);
        }
        if (slot == 0) {
            float dv = dinv[c];
            f16x2 hv = h22[(size_t)c * 8 + f2];
            float2 o;
            o.x = bg[2 * f2]     + dv * (dv * (float)hv[0] + sx);
            o.y = bg[2 * f2 + 1] + dv * (dv * (float)hv[1] + sy);
            ((float2*)out)[(size_t)c * 8 + f2] = o;
        }
        if (!hasN) break;
        c = cn; st = stn; ed = edn; r0 = r0n;
    }
}

extern "C" void kernel_launch(void* const* d_in, const int* in_sizes, int n_in,
                              void* d_out, int out_size, void* d_ws, size_t ws_size,
                              hipStream_t stream) {
    const float* x   = (const float*)d_in[0];
    const int*   ei  = (const int*)d_in[1];
    const float* g1w = (const float*)d_in[2];
    const float* g1b = (const float*)d_in[3];
    const float* ew1 = (const float*)d_in[4];
    const float* eb1 = (const float*)d_in[5];
    const float* ew2 = (const float*)d_in[6];
    const float* eb2 = (const float*)d_in[7];
    const float* g2w = (const float*)d_in[8];
    const float* g2b = (const float*)d_in[9];
    float* out = (float*)d_out;
    float* ws  = (float*)d_ws;

    const int n = in_sizes[0] / 32;      // 50000
    const int E = in_sizes[1] / 2;       // 800000
    const int* row = ei;
    const int* col = ei + E;
    const int ntiles = (n + 15) / 16;    // 3125
    const int nbuck = (n + 127) >> 7;    // 391 buckets of 128 cols

    size_t npad    = ((size_t)n + 63) & ~(size_t)63;
    size_t o_misc  = 0;                         // bcnt[512]
    size_t o_ptr   = 1024;                      // n+1 (+pad)
    size_t o_csr   = o_ptr + npad + 64;         // E ints
    size_t o_dinv  = o_csr + (size_t)E;
    size_t o_atab  = o_dinv + npad;             // n*64 fp16 = n*32 floats
    size_t o_btab  = o_atab + (size_t)n * 32;   // n*64 fp16
    size_t o_agg   = o_btab + (size_t)n * 32;   // n*32 fp32
    size_t o_xh    = o_agg + (size_t)n * 32;    // n*32 fp16 = n*16 floats
    size_t o_h2h   = o_xh + (size_t)n * 16;     // n*16 fp16 = n*8 floats
    size_t o_stage = o_h2h + (size_t)n * 8;     // nbuck*4096 ints (fixed slots)

    int*      bcnt   = (int*)(ws + o_misc);
    int*      ptr    = (int*)(ws + o_ptr);
    int*      csr    = (int*)(ws + o_csr);
    float*    dinv   = ws + o_dinv;
    _Float16* atab   = (_Float16*)(ws + o_atab);
    _Float16* btab   = (_Float16*)(ws + o_btab);
    float*    agg    = ws + o_agg;
    _Float16* xh     = (_Float16*)(ws + o_xh);
    _Float16* h2h    = (_Float16*)(ws + o_h2h);
    int*      stage  = (int*)(ws + o_stage);

    int fill_nb = (E + FILL_CH - 1) / FILL_CH;   // 196
    int m4 = n * 8;                              // x float4 count

    hipMemsetAsync(bcnt, 0, 512 * sizeof(int), stream);
    k_fill_a<<<fill_nb, 256, 0, stream>>>(row, col, (const float4*)x, (f16x4*)xh,
                                          bcnt, stage, E, m4, nbuck);
    k_fill_b2<<<nbuck, 256, 0, stream>>>(bcnt, stage, ptr, dinv, csr, n, nbuck, E);
    k_gather32<<<2048, 256, 0, stream>>>(ptr, csr, x, xh, dinv, agg, n);
    k_h1tab<<<256, 256, 0, stream>>>(agg, g1w, g1b, ew1, eb1, atab, btab, ntiles);
    k_edge_mlp<<<2048, 256, 0, stream>>>(ptr, csr, atab, btab, ew2, eb2, g2w, h2h, n);
    k_gcn2_gather<<<2048, 256, 0, stream>>>(ptr, csr, h2h, dinv, g2b, out, n);
}

// Round 13
// 179.590 us; speedup vs baseline: 1.6941x; 1.0104x over previous
//
#include <hip/hip_runtime.h>

// CSR-gather pipeline (no float atomics):
//   memset(bcnt,2KB) ; fill_a (fixed-slot bucket staging) ; fill_b2 (own-prefix
//   + per-bucket hist/scan -> ptr/dinv/csr + SCALED x->fp16 cast xh'=dinv*x) ;
//   gather32 (persistent+prefetch, no per-edge dinv) ; h1tab (grid 256) ;
//   edge_mlp (persistent+prefetch, stores h2h'=dinv[c]*h2) ; gcn2_gather
//   (persistent+prefetch, no per-edge dinv)
// R13: dinv folded into gathered payloads (gather is linear in dinv):
//     xh' = fp16(dinv[r]*x[r]) written by fill_b2 (which owns dinv);
//     h2h' = fp16(dinv[c]*h2[c]) written by edge_mlp. Removes 2x800k random
//     4B dinv loads and shortens both gathers' dependent chain to csr->row.

typedef __attribute__((ext_vector_type(8))) short short8;
typedef __attribute__((ext_vector_type(4))) float f32x4;
typedef __attribute__((ext_vector_type(8))) _Float16 f16x8;
typedef __attribute__((ext_vector_type(4))) _Float16 f16x4;
typedef __attribute__((ext_vector_type(2))) _Float16 f16x2;

#define FILL_CH 4096      // edges per fill_a block (256 thr x 16)

__device__ __forceinline__ unsigned short f2bf(float x) {   // RNE f32->bf16 (cold paths only)
    unsigned int u = __float_as_uint(x);
    return (unsigned short)((u + 0x7FFFu + ((u >> 16) & 1u)) >> 16);
}
__device__ __forceinline__ float bf2f(unsigned short h) {
    return __uint_as_float(((unsigned int)h) << 16);
}
// cheap truncation split: u ~= hi + lo with |err| ~ 2^-16 |u|
__device__ __forceinline__ void splitT(float u, short& hi, short& lo) {
    unsigned int ub = __float_as_uint(u);
    hi = (short)(ub >> 16);
    float r = u - __uint_as_float(ub & 0xFFFF0000u);
    lo = (short)(__float_as_uint(r) >> 16);
}
__device__ __forceinline__ f16x8 relu8(f16x8 v) {
    f16x8 z = {0, 0, 0, 0, 0, 0, 0, 0};
#if __has_builtin(__builtin_elementwise_max)
    return __builtin_elementwise_max(v, z);
#else
    f16x8 o;
#pragma unroll
    for (int j = 0; j < 8; ++j) o[j] = v[j] > (_Float16)0 ? v[j] : (_Float16)0;
    return o;
#endif
}

// rotate-add within a 16-lane row (DPP row_ror:N); tree 1,2,4,8 == full 16-lane
// sum in every lane. Pure VALU. (row_ror = 0x120+N.)
#define ROR_ADD(s, CTRL)                                                         \
    s += __int_as_float(__builtin_amdgcn_update_dpp(                             \
        0, __float_as_int(s), (CTRL), 0xf, 0xf, false))
#define ROR8_ADD(s) ROR_ADD(s, 0x128)

// fill phase A: bucket edges into FIXED 4096-entry slots.
// stage entry packed: (r << 7) | (c & 127)   [valid for n < 2^25]
__global__ __launch_bounds__(256) void k_fill_a(
        const int* __restrict__ row, const int* __restrict__ col,
        int* __restrict__ bcnt, int* __restrict__ stage, int E, int nb) {
    __shared__ int cnt[512];
    __shared__ int base[512];
    int tid = threadIdx.x;
    for (int i = tid; i < nb; i += 256) cnt[i] = 0;
    __syncthreads();
    int e0 = blockIdx.x * FILL_CH;
    int r[16], c[16];
#pragma unroll
    for (int i = 0; i < 16; ++i) {
        int e = e0 + tid + i * 256;
        if (e < E) {
            r[i] = row[e]; c[i] = col[e];
            atomicAdd(&cnt[c[i] >> 7], 1);
        } else c[i] = -1;
    }
    __syncthreads();
    for (int i = tid; i < nb; i += 256)
        base[i] = cnt[i] ? (i << 12) + atomicAdd(&bcnt[i], cnt[i]) : 0;
    __syncthreads();
#pragma unroll
    for (int i = 0; i < 16; ++i) {
        if (c[i] >= 0) {
            int b = c[i] >> 7;
            int lp = atomicAdd(&base[b], 1);
            stage[lp] = (r[i] << 7) | (c[i] & 127);
        }
    }
}

// fill phase B2: one block per bucket. Own csr base (prefix over bcnt), local
// 128-col hist + scan -> ptr/dinv, scatter csr, then SCALED cast for this
// bucket's nodes: xh'[c] = fp16(dinv[c] * x[c]).
__global__ __launch_bounds__(256) void k_fill_b2(
        const int* __restrict__ bcnt, const int* __restrict__ stage,
        const float4* __restrict__ x4, f16x4* __restrict__ xh4,
        int* __restrict__ ptr, float* __restrict__ dinv, int* __restrict__ csr,
        int n, int nb, int E) {
    __shared__ int lcnt[128];
    __shared__ int lcur[128];
    __shared__ float dinvS[128];
    __shared__ int wtotS;
    __shared__ int wsum[4];
    __shared__ int gbaseS;
    int b = blockIdx.x, tid = threadIdx.x;
    int lane = tid & 63, w = tid >> 6;
    int c0 = b << 7;
    int s0 = b << 12;               // fixed staging slot base
    int tot = bcnt[b];
    if (tid < 128) lcnt[tid] = 0;
    // own prefix: sum bcnt[i] for i < b (bcnt[i>=nb] is poisoned -> mask)
    int acc = 0;
    if (tid < b && tid < nb) acc += bcnt[tid];
    int t2 = tid + 256;
    if (t2 < b && t2 < nb) acc += bcnt[t2];
#pragma unroll
    for (int off = 1; off < 64; off <<= 1) acc += __shfl_xor(acc, off);
    if (lane == 0) wsum[w] = acc;
    __syncthreads();                // lcnt zeroed AND wsum ready
    if (tid == 0) {
        gbaseS = wsum[0] + wsum[1] + wsum[2] + wsum[3];
        if (b == nb - 1) ptr[n] = E;
    }
    for (int p = tid; p < tot; p += 256)
        atomicAdd(&lcnt[stage[s0 + p] & 127], 1);
    __syncthreads();                // hist done; gbaseS visible
    int gbase = gbaseS;
    int v = (tid < 128) ? lcnt[tid] : 0;
    int s = v;
    for (int off = 1; off < 64; off <<= 1) {
        int t = __shfl_up(s, off, 64);
        if (lane >= off) s += t;
    }
    if (tid == 63) wtotS = s;
    __syncthreads();
    int excl = s - v + ((w == 1) ? wtotS : 0);
    if (tid < 128) {
        int c = c0 + tid;
        int basep = gbase + excl;
        lcur[tid] = basep;
        float dv = rsqrtf((float)(v + 1));      // +1 self loop
        dinvS[tid] = dv;
        if (c < n) {
            ptr[c] = basep;
            dinv[c] = dv;
        }
    }
    __syncthreads();                // lcur + dinvS visible
    for (int p = tid; p < tot; p += 256) {
        int vv = stage[s0 + p];
        int pos = atomicAdd(&lcur[vv & 127], 1);
        csr[pos] = vv >> 7;
    }
    // scaled cast: xh'[c] = fp16(dinv[c] * x[c]) for this bucket's nodes
    int cmax = n - c0; if (cmax > 128) cmax = 128;
    for (int i = tid; i < cmax * 8; i += 256) {
        int ci = i >> 3, j = i & 7;
        float dv = dinvS[ci];
        float4 xv = x4[(size_t)(c0 + ci) * 8 + j];
        f16x4 o;
        o[0] = (_Float16)(dv * xv.x); o[1] = (_Float16)(dv * xv.y);
        o[2] = (_Float16)(dv * xv.z); o[3] = (_Float16)(dv * xv.w);
        xh4[(size_t)(c0 + ci) * 8 + j] = o;
    }
}

// irregular gather (pre-scaled fp16 xh'): agg[v] = dv*(sum xh'[r]) + dv^2*x[v]
// persistent waves + next-node ptr/first-csr prefetch; no per-edge dinv load.
__global__ __launch_bounds__(256) void k_gather32(
        const int* __restrict__ ptr, const int* __restrict__ csr_row,
        const float* __restrict__ x, const _Float16* __restrict__ xh,
        const float* __restrict__ dinv, float* __restrict__ agg, int n) {
    int lane = threadIdx.x & 63;
    int f4 = lane & 7, slot = lane >> 3;
    const f16x4* xh4 = (const f16x4*)xh;

    int nwaves = gridDim.x * 4;
    int wid = blockIdx.x * 4 + (threadIdx.x >> 6);
    if (wid >= n) return;

    int c = wid;
    int st = ptr[c], ed = ptr[c + 1];
    int r0 = (st + slot < ed) ? csr_row[st + slot] : 0;
    while (true) {
        // prefetch next node's ptr pair
        int cn = c + nwaves;
        bool hasN = cn < n;
        int stn = 0, edn = 0;
        if (hasN) { stn = ptr[cn]; edn = ptr[cn + 1]; }

        float sx = 0.f, sy = 0.f, sz = 0.f, sw = 0.f;
        int p = st + slot;
        int r = r0;
        while (p < ed) {
            int rcur = r;
            int pn = p + 8;
            if (pn < ed) r = csr_row[pn];
            f16x4 xv = xh4[(size_t)rcur * 8 + f4];
            sx += (float)xv[0];
            sy += (float)xv[1];
            sz += (float)xv[2];
            sw += (float)xv[3];
            p = pn;
        }
        // prefetch next node's first csr batch
        int r0n = 0;
        if (hasN && stn + slot < edn) r0n = csr_row[stn + slot];

        ROR8_ADD(sx); ROR8_ADD(sy); ROR8_ADD(sz); ROR8_ADD(sw);
#pragma unroll
        for (int off = 16; off < 64; off <<= 1) {
            sx += __shfl_xor(sx, off); sy += __shfl_xor(sy, off);
            sz += __shfl_xor(sz, off); sw += __shfl_xor(sw, off);
        }
        if (slot == 0) {
            float dv = dinv[c], d2 = dv * dv;
            float4 xv = ((const float4*)x)[(size_t)c * 8 + f4];
            float4 o;
            o.x = dv * sx + d2 * xv.x;
            o.y = dv * sy + d2 * xv.y;
            o.z = dv * sz + d2 * xv.z;
            o.w = dv * sw + d2 * xv.w;
            ((float4*)agg)[(size_t)c * 8 + f4] = o;
        }
        if (!hasN) break;
        c = cn; st = stn; ed = edn; r0 = r0n;
    }
}

// FUSED dense MFMA: h1 = tanh(agg @ Wg1 + gb) ; atab = h1@(W1a-W1b)+b1 ;
// btab = h1@W1b (fp16 out). Wave-private LDS tile for C/D->A transform.
__global__ __launch_bounds__(256, 1) void k_h1tab(
        const float* __restrict__ agg, const float* __restrict__ gw,
        const float* __restrict__ gb, const float* __restrict__ w1,
        const float* __restrict__ b1,
        _Float16* __restrict__ atab, _Float16* __restrict__ btab, int ntiles) {
    __shared__ float tileS[4][16 * 66];
    int lane = threadIdx.x & 63;
    int wv = threadIdx.x >> 6;
    int n16 = lane & 15, q = lane >> 4;
    float* T = tileS[wv];

    short8 gh[4], gl[4];
    float gbias[4];
#pragma unroll
    for (int t = 0; t < 4; ++t) {
        gbias[t] = gb[t * 16 + n16];
        short8 hh, ll;
#pragma unroll
        for (int j = 0; j < 8; ++j) {
            float w = gw[(q * 8 + j) * 64 + t * 16 + n16];
            unsigned short wh = f2bf(w);
            hh[j] = (short)wh;
            ll[j] = (short)f2bf(w - bf2f(wh));
        }
        gh[t] = hh; gl[t] = ll;
    }
    short8 th[4][2], tl[4][2], uh[4][2], ul[4][2];
    float bias1[4];
#pragma unroll
    for (int t = 0; t < 4; ++t) {
        bias1[t] = b1[t * 16 + n16];
#pragma unroll
        for (int ck = 0; ck < 2; ++ck) {
            short8 h1v, l1v, h2v, l2v;
#pragma unroll
            for (int j = 0; j < 8; ++j) {
                int d = ck * 32 + q * 8 + j;
                float wbv = w1[(64 + d) * 64 + t * 16 + n16];
                float wtv = w1[d * 64 + t * 16 + n16] - wbv;
                unsigned short x1 = f2bf(wtv);
                h1v[j] = (short)x1; l1v[j] = (short)f2bf(wtv - bf2f(x1));
                unsigned short x2 = f2bf(wbv);
                h2v[j] = (short)x2; l2v[j] = (short)f2bf(wbv - bf2f(x2));
            }
            th[t][ck] = h1v; tl[t][ck] = l1v;
            uh[t][ck] = h2v; ul[t][ck] = l2v;
        }
    }

    int nwaves = gridDim.x * 4;
    int wid = blockIdx.x * 4 + wv;
    for (int tile = wid; tile < ntiles; tile += nwaves) {
        int v0 = tile * 16;
        const float4* a4 = (const float4*)(agg + (size_t)(v0 + n16) * 32);
        float4 A0 = a4[2 * q], A1 = a4[2 * q + 1];
        float a[8] = {A0.x, A0.y, A0.z, A0.w, A1.x, A1.y, A1.z, A1.w};
        short8 ah, al;
#pragma unroll
        for (int j = 0; j < 8; ++j) { short h, l; splitT(a[j], h, l); ah[j] = h; al[j] = l; }
#pragma unroll
        for (int t = 0; t < 4; ++t) {
            f32x4 acc = (f32x4){gbias[t], gbias[t], gbias[t], gbias[t]};
            acc = __builtin_amdgcn_mfma_f32_16x16x32_bf16(ah, gh[t], acc, 0, 0, 0);
            acc = __builtin_amdgcn_mfma_f32_16x16x32_bf16(al, gh[t], acc, 0, 0, 0);
            acc = __builtin_amdgcn_mfma_f32_16x16x32_bf16(ah, gl[t], acc, 0, 0, 0);
#pragma unroll
            for (int i = 0; i < 4; ++i)
                T[(q * 4 + i) * 66 + t * 16 + n16] = tanhf(acc[i]);
        }
        float b[16];
#pragma unroll
        for (int j = 0; j < 8; ++j) {
            b[j]     = T[n16 * 66 + q * 8 + j];
            b[8 + j] = T[n16 * 66 + 32 + q * 8 + j];
        }
        short8 ah0, ah1, al0, al1;
#pragma unroll
        for (int j = 0; j < 8; ++j) {
            short h, l;
            splitT(b[j], h, l);      ah0[j] = h; al0[j] = l;
            splitT(b[8 + j], h, l);  ah1[j] = h; al1[j] = l;
        }
#pragma unroll
        for (int t = 0; t < 4; ++t) {
            f32x4 aa = (f32x4){bias1[t], bias1[t], bias1[t], bias1[t]};
            aa = __builtin_amdgcn_mfma_f32_16x16x32_bf16(ah0, th[t][0], aa, 0, 0, 0);
            aa = __builtin_amdgcn_mfma_f32_16x16x32_bf16(ah1, th[t][1], aa, 0, 0, 0);
            aa = __builtin_amdgcn_mfma_f32_16x16x32_bf16(al0, th[t][0], aa, 0, 0, 0);
            aa = __builtin_amdgcn_mfma_f32_16x16x32_bf16(al1, th[t][1], aa, 0, 0, 0);
            aa = __builtin_amdgcn_mfma_f32_16x16x32_bf16(ah0, tl[t][0], aa, 0, 0, 0);
            aa = __builtin_amdgcn_mfma_f32_16x16x32_bf16(ah1, tl[t][1], aa, 0, 0, 0);
            f32x4 bb = (f32x4){0.f, 0.f, 0.f, 0.f};
            bb = __builtin_amdgcn_mfma_f32_16x16x32_bf16(ah0, uh[t][0], bb, 0, 0, 0);
            bb = __builtin_amdgcn_mfma_f32_16x16x32_bf16(ah1, uh[t][1], bb, 0, 0, 0);
            bb = __builtin_amdgcn_mfma_f32_16x16x32_bf16(al0, uh[t][0], bb, 0, 0, 0);
            bb = __builtin_amdgcn_mfma_f32_16x16x32_bf16(al1, uh[t][1], bb, 0, 0, 0);
            bb = __builtin_amdgcn_mfma_f32_16x16x32_bf16(ah0, ul[t][0], bb, 0, 0, 0);
            bb = __builtin_amdgcn_mfma_f32_16x16x32_bf16(ah1, ul[t][1], bb, 0, 0, 0);
#pragma unroll
            for (int i = 0; i < 4; ++i) {
                size_t off = (size_t)(v0 + q * 4 + i) * 64 + t * 16 + n16;
                atab[off] = (_Float16)aa[i];
                btab[off] = (_Float16)bb[i];
            }
        }
    }
}

// persistent waves; fp16 MFMA (fp32 acc, zero-C, bias after max); setprio;
// node-level ptr/csr/dinv prefetch; stores h2h' = dinv[c]*h2[c] (fp16).
__global__ __launch_bounds__(256) void k_edge_mlp(
        const int* __restrict__ ptr, const int* __restrict__ csr_row,
        const _Float16* __restrict__ atab, const _Float16* __restrict__ btab,
        const float* __restrict__ w2, const float* __restrict__ b2,
        const float* __restrict__ wg, const float* __restrict__ dinv,
        _Float16* __restrict__ h2h, int n) {
    int lane = threadIdx.x & 63;
    int n16 = lane & 15, q = lane >> 4;

    f16x8 wh[4][2];
    float bias[4];
    float wgf[4][4];    // Wg2 rows {t*16+n16}, cols {q*4+jj}
#pragma unroll
    for (int t = 0; t < 4; ++t) {
        bias[t] = b2[t * 16 + n16];
#pragma unroll
        for (int jj = 0; jj < 4; ++jj)
            wgf[t][jj] = wg[(t * 16 + n16) * 16 + q * 4 + jj];
#pragma unroll
        for (int ck = 0; ck < 2; ++ck) {
            f16x8 hh;
#pragma unroll
            for (int j = 0; j < 8; ++j)
                hh[j] = (_Float16)w2[(ck * 32 + q * 8 + j) * 64 + t * 16 + n16];
            wh[t][ck] = hh;
        }
    }
    const f32x4 z4 = (f32x4){0.f, 0.f, 0.f, 0.f};

    int nwaves = gridDim.x * 4;
    int wid = blockIdx.x * 4 + (threadIdx.x >> 6);
    if (wid >= n) return;

    // prologue: node `wid`'s ptr + dinv + both csr levels
    int c = wid;
    int st = ptr[c], ed = ptr[c + 1];
    float dv = dinv[c];
    {
        int deg = ed - st;
        int nf = deg >> 4, rm = deg & 15;
        int rrem0 = (rm > 0 && n16 < rm) ? csr_row[st + (nf << 4) + n16] : 0;
        int r0 = (nf > 0) ? csr_row[st + n16] : 0;
        int r = r0, rrem = rrem0;
        while (true) {
            // ---- prefetch next node's ptr pair + dinv (independent) ----
            int cn = c + nwaves;
            bool hasN = cn < n;
            int stn = 0, edn = 0;
            float dvn = 0.f;
            if (hasN) { stn = ptr[cn]; edn = ptr[cn + 1]; dvn = dinv[cn]; }

            const f16x8* a8 = (const f16x8*)(atab + (size_t)c * 64);
            f16x8 A0 = a8[q], A1 = a8[4 + q];
            float red[4] = {0.f, 0.f, 0.f, 0.f};   // 0-init folds relu + empty-seg

            int deg2 = ed - st;
            int nfull = deg2 >> 4;
            int rem = deg2 & 15;
            for (int ft = 0; ft < nfull; ++ft) {
                int rcur = r;
                if (ft + 1 < nfull) r = csr_row[st + (ft + 1) * 16 + n16];
                const f16x8* b8 = (const f16x8*)(btab + (size_t)rcur * 64);
                f16x8 u0 = relu8(A0 + b8[q]);
                f16x8 u1 = relu8(A1 + b8[4 + q]);
                __builtin_amdgcn_s_setprio(1);
#pragma unroll
                for (int t = 0; t < 4; ++t) {
                    f32x4 a = __builtin_amdgcn_mfma_f32_16x16x32_f16(u0, wh[t][0], z4, 0, 0, 0);
                    a = __builtin_amdgcn_mfma_f32_16x16x32_f16(u1, wh[t][1], a, 0, 0, 0);
                    float mx = fmaxf(fmaxf(a[0], a[1]), fmaxf(a[2], a[3]));
                    red[t] = fmaxf(red[t], mx + bias[t]);
                }
                __builtin_amdgcn_s_setprio(0);
            }
            if (rem > 0) {
                f16x8 u0 = {0, 0, 0, 0, 0, 0, 0, 0};
                f16x8 u1 = {0, 0, 0, 0, 0, 0, 0, 0};
                if (n16 < rem) {
                    const f16x8* b8 = (const f16x8*)(btab + (size_t)rrem * 64);
                    u0 = relu8(A0 + b8[q]);
                    u1 = relu8(A1 + b8[4 + q]);
                }
                __builtin_amdgcn_s_setprio(1);
#pragma unroll
                for (int t = 0; t < 4; ++t) {
                    f32x4 a = __builtin_amdgcn_mfma_f32_16x16x32_f16(u0, wh[t][0], z4, 0, 0, 0);
                    a = __builtin_amdgcn_mfma_f32_16x16x32_f16(u1, wh[t][1], a, 0, 0, 0);
#pragma unroll
                    for (int i = 0; i < 4; ++i)
                        if (q * 4 + i < rem) red[t] = fmaxf(red[t], a[i] + bias[t]);
                }
                __builtin_amdgcn_s_setprio(0);
            }

            // ---- prefetch next node's csr (stn/edn arrived during MFMA) ----
            int rn = 0, rremn = 0;
            if (hasN) {
                int degn = edn - stn;
                int nfn = degn >> 4, rmn = degn & 15;
                if (rmn > 0 && n16 < rmn) rremn = csr_row[stn + (nfn << 4) + n16];
                if (nfn > 0) rn = csr_row[stn + n16];
            }

            // ---- epilogue: segment-max across q, fused GCN2, scaled store ----
#pragma unroll
            for (int t = 0; t < 4; ++t) {
                red[t] = fmaxf(red[t], __shfl_xor(red[t], 16));
                red[t] = fmaxf(red[t], __shfl_xor(red[t], 32));
            }
            float part[4];
#pragma unroll
            for (int jj = 0; jj < 4; ++jj) {
                part[jj] = red[0] * wgf[0][jj];
                part[jj] = fmaf(red[1], wgf[1][jj], part[jj]);
                part[jj] = fmaf(red[2], wgf[2][jj], part[jj]);
                part[jj] = fmaf(red[3], wgf[3][jj], part[jj]);
                ROR_ADD(part[jj], 0x121);
                ROR_ADD(part[jj], 0x122);
                ROR_ADD(part[jj], 0x124);
                ROR_ADD(part[jj], 0x128);
            }
            if (n16 == 0) {
                f16x4 ph;
                ph[0] = (_Float16)(dv * part[0]); ph[1] = (_Float16)(dv * part[1]);
                ph[2] = (_Float16)(dv * part[2]); ph[3] = (_Float16)(dv * part[3]);
                ((f16x4*)(h2h + (size_t)c * 16))[q] = ph;
            }

            if (!hasN) break;
            c = cn; st = stn; ed = edn; r = rn; rrem = rremn; dv = dvn;
        }
    }
}

// out[c] = bg + dv*(h2h'[c] + sum_in h2h'[r])  [h2h' = dinv*h2, pre-scaled]
// persistent waves + next-node ptr/first-csr prefetch; no per-edge dinv.
__global__ __launch_bounds__(256) void k_gcn2_gather(
        const int* __restrict__ ptr, const int* __restrict__ csr_row,
        const _Float16* __restrict__ h2h, const float* __restrict__ dinv,
        const float* __restrict__ bg, float* __restrict__ out, int n) {
    int lane = threadIdx.x & 63;
    int f2 = lane & 7, slot = lane >> 3;
    const f16x2* h22 = (const f16x2*)h2h;

    int nwaves = gridDim.x * 4;
    int wid = blockIdx.x * 4 + (threadIdx.x >> 6);
    if (wid >= n) return;

    int c = wid;
    int st = ptr[c], ed = ptr[c + 1];
    int r0 = (st + slot < ed) ? csr_row[st + slot] : 0;
    while (true) {
        int cn = c + nwaves;
        bool hasN = cn < n;
        int stn = 0, edn = 0;
        if (hasN) { stn = ptr[cn]; edn = ptr[cn + 1]; }

        float sx = 0.f, sy = 0.f;
        int p = st + slot;
        int r = r0;
        while (p < ed) {
            int rcur = r;
            int pn = p + 8;
            if (pn < ed) r = csr_row[pn];
            f16x2 hv = h22[(size_t)rcur * 8 + f2];
            sx += (float)hv[0];
            sy += (float)hv[1];
            p = pn;
        }
        int r0n = 0;
        if (hasN && stn + slot < edn) r0n = csr_row[stn + slot];

        ROR8_ADD(sx); ROR8_ADD(sy);
#pragma unroll
        for (int off = 16; off < 64; off <<= 1) {
            sx += __shfl_xor(sx, off);
            sy += __shfl_xor(sy, off);
        }
        if (slot == 0) {
            float dv = dinv[c];
            f16x2 hv = h22[(size_t)c * 8 + f2];
            float2 o;
            o.x = bg[2 * f2]     + dv * ((float)hv[0] + sx);
            o.y = bg[2 * f2 + 1] + dv * ((float)hv[1] + sy);
            ((float2*)out)[(size_t)c * 8 + f2] = o;
        }
        if (!hasN) break;
        c = cn; st = stn; ed = edn; r0 = r0n;
    }
}

extern "C" void kernel_launch(void* const* d_in, const int* in_sizes, int n_in,
                              void* d_out, int out_size, void* d_ws, size_t ws_size,
                              hipStream_t stream) {
    const float* x   = (const float*)d_in[0];
    const int*   ei  = (const int*)d_in[1];
    const float* g1w = (const float*)d_in[2];
    const float* g1b = (const float*)d_in[3];
    const float* ew1 = (const float*)d_in[4];
    const float* eb1 = (const float*)d_in[5];
    const float* ew2 = (const float*)d_in[6];
    const float* eb2 = (const float*)d_in[7];
    const float* g2w = (const float*)d_in[8];
    const float* g2b = (const float*)d_in[9];
    float* out = (float*)d_out;
    float* ws  = (float*)d_ws;

    const int n = in_sizes[0] / 32;      // 50000
    const int E = in_sizes[1] / 2;       // 800000
    const int* row = ei;
    const int* col = ei + E;
    const int ntiles = (n + 15) / 16;    // 3125
    const int nbuck = (n + 127) >> 7;    // 391 buckets of 128 cols

    size_t npad    = ((size_t)n + 63) & ~(size_t)63;
    size_t o_misc  = 0;                         // bcnt[512]
    size_t o_ptr   = 1024;                      // n+1 (+pad)
    size_t o_csr   = o_ptr + npad + 64;         // E ints
    size_t o_dinv  = o_csr + (size_t)E;
    size_t o_atab  = o_dinv + npad;             // n*64 fp16 = n*32 floats
    size_t o_btab  = o_atab + (size_t)n * 32;   // n*64 fp16
    size_t o_agg   = o_btab + (size_t)n * 32;   // n*32 fp32
    size_t o_xh    = o_agg + (size_t)n * 32;    // n*32 fp16 = n*16 floats
    size_t o_h2h   = o_xh + (size_t)n * 16;     // n*16 fp16 = n*8 floats
    size_t o_stage = o_h2h + (size_t)n * 8;     // nbuck*4096 ints (fixed slots)

    int*      bcnt   = (int*)(ws + o_misc);
    int*      ptr    = (int*)(ws + o_ptr);
    int*      csr    = (int*)(ws + o_csr);
    float*    dinv   = ws + o_dinv;
    _Float16* atab   = (_Float16*)(ws + o_atab);
    _Float16* btab   = (_Float16*)(ws + o_btab);
    float*    agg    = ws + o_agg;
    _Float16* xh     = (_Float16*)(ws + o_xh);
    _Float16* h2h    = (_Float16*)(ws + o_h2h);
    int*      stage  = (int*)(ws + o_stage);

    int fill_nb = (E + FILL_CH - 1) / FILL_CH;   // 196

    hipMemsetAsync(bcnt, 0, 512 * sizeof(int), stream);
    k_fill_a<<<fill_nb, 256, 0, stream>>>(row, col, bcnt, stage, E, nbuck);
    k_fill_b2<<<nbuck, 256, 0, stream>>>(bcnt, stage, (const float4*)x, (f16x4*)xh,
                                         ptr, dinv, csr, n, nbuck, E);
    k_gather32<<<2048, 256, 0, stream>>>(ptr, csr, x, xh, dinv, agg, n);
    k_h1tab<<<256, 256, 0, stream>>>(agg, g1w, g1b, ew1, eb1, atab, btab, ntiles);
    k_edge_mlp<<<2048, 256, 0, stream>>>(ptr, csr, atab, btab, ew2, eb2, g2w,
                                         dinv, h2h, n);
    k_gcn2_gather<<<2048, 256, 0, stream>>>(ptr, csr, h2h, dinv, g2b, out, n);
}